// Round 12
// baseline (1861.807 us; speedup 1.0000x reference)
//
#include <hip/hip_runtime.h>
#include <math.h>

#define NFFT  512
#define WINL  320
#define HOP   160
#define FPAD  256
#define NF    257
#define TT    601
#define LSEQ  96000
#define XPLEN 96512
#define NCH   8
#define NB    8
#define NSEQ  64
#define NROWS 38464   // NSEQ*TT
#define DD    514
#define HH    128
#define G4    512
#define KPAD  544     // 17*32, zero-padded K for split-B arrays

typedef _Float16 h2v __attribute__((ext_vector_type(2)));
typedef _Float16 f16x8 __attribute__((ext_vector_type(8)));
typedef short bf16x8 __attribute__((ext_vector_type(8)));
typedef float f32x4 __attribute__((ext_vector_type(4)));

// ---------------- init helpers ----------------
__device__ __forceinline__ float winval(int k) {
  if (k < 96 || k >= 416) return 0.f;
  return 0.5f - 0.5f * cosf((float)(2.0 * M_PI / 320.0) * (float)(k - 96));
}

__device__ __forceinline__ void split_bf16(float v, unsigned short* h, unsigned short* l) {
  unsigned int hb = __float_as_uint(v) >> 16;
  float r = v - __uint_as_float(hb << 16);
  *h = (unsigned short)hb;
  *l = (unsigned short)(__float_as_uint(r) >> 16);
}

__global__ void k_wsq(float* __restrict__ wsq) {
  int p = blockIdx.x * 256 + threadIdx.x;
  if (p >= XPLEN) return;
  int t0 = (p <= 511) ? 0 : (p - 352) / 160;
  int t1 = p / 160; if (t1 > 600) t1 = 600;
  float s = 0.f;
  for (int t = t0; t <= t1; t++) { float w = winval(p - t * HOP); s += w * w; }
  wsq[p] = s;
}

// BF split: Bt[n][k] = DFT-forward[k][n]
__global__ void k_bfsplit(unsigned short* __restrict__ H, unsigned short* __restrict__ L) {
  int idx = blockIdx.x * 256 + threadIdx.x;
  if (idx >= 640 * KPAD) return;
  int n = idx / KPAD, k = idx - n * KPAD;
  float v = 0.f;
  if (n < DD && k < NFFT) {
    float w = winval(k);
    int f = (n < NF) ? n : n - NF;
    int m = (k * f) & 511;
    float th = (float)(M_PI / 256.0) * (float)m;
    v = ((n < NF) ? cosf(th) : -sinf(th)) * w;
  }
  split_bf16(v, &H[idx], &L[idx]);
}

// WT split: Bt[n][k] = Wih[n][k]
__global__ void k_wtsplit(const float* __restrict__ Wih, unsigned short* __restrict__ H,
                          unsigned short* __restrict__ L) {
  int idx = blockIdx.x * 256 + threadIdx.x;
  if (idx >= G4 * KPAD) return;
  int n = idx / KPAD, k = idx - n * KPAD;
  float v = (k < DD) ? Wih[n * DD + k] : 0.f;
  split_bf16(v, &H[idx], &L[idx]);
}

// BI split: Bt[n][kk] = BI[kk][n]
__global__ void k_bisplit(unsigned short* __restrict__ H, unsigned short* __restrict__ L) {
  int idx = blockIdx.x * 256 + threadIdx.x;
  if (idx >= NFFT * KPAD) return;
  int n = idx / KPAD, kk = idx - n * KPAD;
  float v = 0.f;
  if (kk < DD) {
    float w = winval(n);
    int f = (kk < NF) ? kk : kk - NF;
    int edge = (f == 0 || f == 256);
    float alpha = edge ? 1.f : 2.f;
    int m = (n * f) & 511;
    float th = (float)(M_PI / 256.0) * (float)m;
    float c;
    if (kk < NF) c = alpha * cosf(th);
    else         c = edge ? 0.f : -alpha * sinf(th);
    v = c * w * (1.f / 512.f);
  }
  split_bf16(v, &H[idx], &L[idx]);
}

__global__ void k_bsum(const float* __restrict__ bih, const float* __restrict__ bhh,
                       float* __restrict__ BSUM) {
  int idx = blockIdx.x * 256 + threadIdx.x;
  if (idx < G4) BSUM[idx] = bih[idx] + bhh[idx];
}

// W1/W2 mask-weight split: Ws[n'][k], n' = ri*320 + f (ri=0 real, 1 imag), k<128
__global__ void k_wmsplit(const float* __restrict__ W1, const float* __restrict__ W2,
                          unsigned short* __restrict__ W1h, unsigned short* __restrict__ W1l,
                          unsigned short* __restrict__ W2h, unsigned short* __restrict__ W2l) {
  int idx = blockIdx.x * 256 + threadIdx.x;
  if (idx >= 2 * 640 * HH) return;
  int m = idx / (640 * HH);
  int rem = idx - m * 640 * HH;
  int np = rem / HH, k = rem - np * HH;
  int ri = np / 320, f = np - ri * 320;
  float v = 0.f;
  if (f < NF) {
    int fcol = (ri == 0) ? f : NF + f;
    v = (m == 0) ? W1[fcol * HH + k] : W2[fcol * HH + k];
  }
  unsigned short h, l;
  split_bf16(v, &h, &l);
  if (m == 0) { W1h[rem] = h; W1l[rem] = l; }
  else        { W2h[rem] = h; W2l[rem] = l; }
}

// Pack Whh into f16 B-fragment order for the MFMA LSTM:
// frag fidx = w*16 + ct*4 + kf; lane holds B[k=kf*32+(lane>>4)*8+jj][n=w*64+ct*16+(lane&15)]
// = Whh[n][k], jj=0..7 -> uint j2 packs (jj=2*j2, 2*j2+1).
__global__ void k_wfrag(const float* __restrict__ Whh, unsigned int* __restrict__ WF) {
  int idx = blockIdx.x * 256 + threadIdx.x;
  if (idx >= 32768) return;
  int j2 = idx & 3;
  int lane = (idx >> 2) & 63;
  int fidx = idx >> 8;
  int kf = fidx & 3, ct = (fidx >> 2) & 3, w = fidx >> 4;
  int n = w * 64 + ct * 16 + (lane & 15);
  int k = kf * 32 + (lane >> 4) * 8 + 2 * j2;
  _Float16 lo = (_Float16)Whh[n * HH + k];
  _Float16 hi = (_Float16)Whh[n * HH + k + 1];
  WF[idx] = ((unsigned int)__builtin_bit_cast(unsigned short, hi) << 16)
          |  (unsigned int)__builtin_bit_cast(unsigned short, lo);
}

// reflect-padded multichannel extraction: XP[n][i], n=b*8+c
__global__ void k_xp(const float* __restrict__ x, float* __restrict__ XP) {
  int idx = blockIdx.x * 256 + threadIdx.x;
  if (idx >= NSEQ * XPLEN) return;
  int n = idx / XPLEN, i = idx - n * XPLEN;
  int j = i - FPAD;
  if (j < 0) j = -j;
  else if (j >= LSEQ) j = 2 * LSEQ - 2 - j;
  int b = n >> 3, c = n & 7;
  XP[idx] = x[((long)b * LSEQ + j) * NCH + c];
}

// ---------------- split-bf16 MFMA GEMM: C[M,N] = A[M,K] * Bt^T (+bias) ----------------
template <int GATHER>
__launch_bounds__(256)
__global__ void k_gemm3(const float* __restrict__ A,
                        const unsigned short* __restrict__ Bth,
                        const unsigned short* __restrict__ Btl,
                        const float* __restrict__ bias, float* __restrict__ C,
                        int M, int N, int K, int lda, int ldc) {
  __shared__ __align__(16) unsigned short sAh[128 * 40];
  __shared__ __align__(16) unsigned short sAl[128 * 40];
  __shared__ __align__(16) unsigned short sBh[128 * 40];
  __shared__ __align__(16) unsigned short sBl[128 * 40];
  const int tid = threadIdx.x;
  const int row0 = blockIdx.y * 128, col0 = blockIdx.x * 128;
  const int sar = tid >> 1, sak = (tid & 1) * 16;
  const int arow = row0 + sar;
  long abase;
  if (GATHER) { int nn = arow / TT; int t = arow - nn * TT; abase = (long)nn * XPLEN + (long)t * HOP; }
  else        { abase = (long)arow * lda; }
  const bool arok = (arow < M);
  const int lane = tid & 63, w = tid >> 6;
  const int wm = (w >> 1) * 64, wn = (w & 1) * 64;
  const int l15 = lane & 15, quad = lane >> 4;
  f32x4 acc[4][4] = {};
  unsigned int* aH = (unsigned int*)sAh;
  unsigned int* aL = (unsigned int*)sAl;
  uint4* bH = (uint4*)sBh;
  uint4* bL = (uint4*)sBl;
  for (int k0 = 0; k0 < K; k0 += 32) {
#pragma unroll
    for (int i = 0; i < 8; i++) {
      int kk = k0 + sak + 2 * i;
      float v0 = 0.f, v1 = 0.f;
      if (arok) {
        if (kk + 1 < K) { float2 t2 = *(const float2*)(A + abase + kk); v0 = t2.x; v1 = t2.y; }
        else if (kk < K) { v0 = A[abase + kk]; }
      }
      unsigned int h0 = __float_as_uint(v0) >> 16, h1 = __float_as_uint(v1) >> 16;
      float r0 = v0 - __uint_as_float(h0 << 16), r1 = v1 - __uint_as_float(h1 << 16);
      unsigned int l0 = __float_as_uint(r0) >> 16, l1 = __float_as_uint(r1) >> 16;
      aH[sar * 20 + (sak >> 1) + i] = h0 | (h1 << 16);
      aL[sar * 20 + (sak >> 1) + i] = l0 | (l1 << 16);
    }
#pragma unroll
    for (int h = 0; h < 2; h++) {
      int idx = tid + h * 256;
      int r = idx >> 2, c = idx & 3;
      long go = (long)(col0 + r) * KPAD + k0 + c * 8;
      bH[r * 5 + c] = *(const uint4*)(Bth + go);
      bL[r * 5 + c] = *(const uint4*)(Btl + go);
    }
    __syncthreads();
    bf16x8 ah[4], al[4], bh[4], bl[4];
#pragma unroll
    for (int i = 0; i < 4; i++) {
      int off = (wm + i * 16 + l15) * 40 + quad * 8;
      ah[i] = *(const bf16x8*)(sAh + off);
      al[i] = *(const bf16x8*)(sAl + off);
      int boff = (wn + i * 16 + l15) * 40 + quad * 8;
      bh[i] = *(const bf16x8*)(sBh + boff);
      bl[i] = *(const bf16x8*)(sBl + boff);
    }
#pragma unroll
    for (int i = 0; i < 4; i++)
#pragma unroll
      for (int j = 0; j < 4; j++) {
        acc[i][j] = __builtin_amdgcn_mfma_f32_16x16x32_bf16(al[i], bh[j], acc[i][j], 0, 0, 0);
        acc[i][j] = __builtin_amdgcn_mfma_f32_16x16x32_bf16(ah[i], bl[j], acc[i][j], 0, 0, 0);
        acc[i][j] = __builtin_amdgcn_mfma_f32_16x16x32_bf16(ah[i], bh[j], acc[i][j], 0, 0, 0);
      }
    __syncthreads();
  }
#pragma unroll
  for (int i = 0; i < 4; i++)
#pragma unroll
    for (int j = 0; j < 4; j++) {
      int cc = col0 + wn + j * 16 + l15;
      if (cc >= N) continue;
      float bv = bias ? bias[cc] : 0.f;
#pragma unroll
      for (int rg = 0; rg < 4; rg++) {
        int rr = row0 + wm + i * 16 + quad * 4 + rg;
        if (rr < M) C[(long)rr * ldc + cc] = acc[i][j][rg] + bv;
      }
    }
}

// ---------------- LSTM v9: MFMA-batched, 8 seqs/block ----------------
// dot2 plateau was the 256 MACs/cyc/CU VALU ceiling (r5-r10). MFMA does ~4050 MACs/cyc/CU.
// 8 blocks x 512 thr (8 waves). Per step: G[8x512] = H[8x128]_f16 @ WhhT_f16 via
// mfma_f32_16x16x32_f16 (A rows 8..15 stay zero; C rows 8..15 never read).
// Weights: fragment-order global -> LDS once -> B-frags in 64 VGPRs (LDS refetch fallback).
// H: f16 A-frag buffer in LDS (m89-verified A layout); G stored [n][s] -> acc writes are
// single ds_write_b128; activation threads own fixed (s,j) pairs, c-state in registers.
__device__ __forceinline__ float tanh_fast(float x) {
  float e = __expf(2.f * x);
  return 1.f - 2.f / (e + 1.f);
}

__launch_bounds__(512, 2)
__global__ void k_lstm(const float* __restrict__ XW, const unsigned int* __restrict__ WF,
                       float* __restrict__ Hout) {
  __shared__ unsigned int wlds[32768];   // 128 KB weight fragments
  __shared__ _Float16 alds[2048];        // 4 KB h (A-fragment layout)
  __shared__ float G[4096];              // 16 KB gates [n][s]
  const int tid = threadIdx.x;
  const int blk = blockIdx.x;            // seqs blk*8 .. blk*8+7
  const int lane = tid & 63, w = tid >> 6;
  const int l15 = lane & 15, quad = lane >> 4;
#pragma unroll 8
  for (int i = 0; i < 64; i++) wlds[i * 512 + tid] = WF[i * 512 + tid];
  ((unsigned int*)alds)[tid] = 0u;
  ((unsigned int*)alds)[512 + tid] = 0u;
  __syncthreads();
  f16x8 bfr[4][4];   // [ct][kf]
#pragma unroll
  for (int ct = 0; ct < 4; ct++)
#pragma unroll
    for (int kf = 0; kf < 4; kf++)
      bfr[ct][kf] = *(const f16x8*)&wlds[(((w * 16) + ct * 4 + kf) * 64 + lane) * 4];
  const int s0 = tid >> 7;       // 0..3 (and s0+4)
  const int j0 = tid & 127;
  float cst0 = 0.f, cst1 = 0.f;
  const long xwB = (long)(blk * 8) * TT * G4;
  const int nbase = w * 64 + l15;
  float* Hb = Hout + (long)(blk * 8) * TT * HH;
  const int aslot = (j0 >> 5) * 512 + ((j0 >> 3) & 3) * 128 + (j0 & 7);
  for (int t = 0; t < TT; t++) {
    float xwv[4][4];
    if (quad < 2) {
#pragma unroll
      for (int ct = 0; ct < 4; ct++)
#pragma unroll
        for (int rg = 0; rg < 4; rg++) {
          int s = quad * 4 + rg;
          xwv[ct][rg] = XW[xwB + ((long)s * TT + t) * G4 + nbase + ct * 16];
        }
    }
    f16x8 afr[4];
#pragma unroll
    for (int kf = 0; kf < 4; kf++)
      afr[kf] = *(const f16x8*)&alds[kf * 512 + lane * 8];
    f32x4 acc[4] = {};
#pragma unroll
    for (int ct = 0; ct < 4; ct++)
#pragma unroll
      for (int kf = 0; kf < 4; kf++)
        acc[ct] = __builtin_amdgcn_mfma_f32_16x16x32_f16(afr[kf], bfr[ct][kf], acc[ct], 0, 0, 0);
    if (quad < 2) {
#pragma unroll
      for (int ct = 0; ct < 4; ct++) {
        f32x4 v = acc[ct];
        v[0] += xwv[ct][0]; v[1] += xwv[ct][1]; v[2] += xwv[ct][2]; v[3] += xwv[ct][3];
        *(f32x4*)&G[(nbase + ct * 16) * 8 + quad * 4] = v;
      }
    }
    __syncthreads();
    {
      float gi = G[j0 * 8 + s0],         gf = G[(128 + j0) * 8 + s0];
      float gg = G[(256 + j0) * 8 + s0], go = G[(384 + j0) * 8 + s0];
      float si = 1.f / (1.f + __expf(-gi));
      float sf = 1.f / (1.f + __expf(-gf));
      float so = 1.f / (1.f + __expf(-go));
      cst0 = sf * cst0 + si * tanh_fast(gg);
      float h0 = so * tanh_fast(cst0);
      alds[aslot + s0 * 8] = (_Float16)h0;
      Hb[((long)s0 * TT + t) * HH + j0] = h0;
      int s1 = s0 + 4;
      gi = G[j0 * 8 + s1];         gf = G[(128 + j0) * 8 + s1];
      gg = G[(256 + j0) * 8 + s1]; go = G[(384 + j0) * 8 + s1];
      si = 1.f / (1.f + __expf(-gi));
      sf = 1.f / (1.f + __expf(-gf));
      so = 1.f / (1.f + __expf(-go));
      cst1 = sf * cst1 + si * tanh_fast(gg);
      float h1 = so * tanh_fast(cst1);
      alds[aslot + s1 * 8] = (_Float16)h1;
      Hb[((long)s1 * TT + t) * HH + j0] = h1;
    }
    __syncthreads();
  }
}

// ---------------- mask GEMM (split-bf16 MFMA) + mask apply + transpose ----------------
__launch_bounds__(256)
__global__ void k_maskms(const float* __restrict__ Hout,
                         const unsigned short* __restrict__ Wsh,
                         const unsigned short* __restrict__ Wsl,
                         const float* __restrict__ bias, const float* __restrict__ S,
                         float* __restrict__ MS) {
  __shared__ __align__(16) unsigned short sAh[64 * 40];
  __shared__ __align__(16) unsigned short sAl[64 * 40];
  __shared__ __align__(16) unsigned short sBh[64 * 40];
  __shared__ __align__(16) unsigned short sBl[64 * 40];
  __shared__ float Cs[64][68];
  __shared__ float SR[64][33];
  __shared__ float SI[64][33];
  const int tid = threadIdx.x;
  const int f0 = blockIdx.x * 32;
  const int row0 = blockIdx.y * 64;
  const int lane = tid & 63, w = tid >> 6;
  const int wm = w * 16;
  const int l15 = lane & 15, quad = lane >> 4;
  const int sar = tid >> 2;
  const int sak = (tid & 3) * 8;
  const int np = ((sar < 32) ? 0 : 320 - 32) + f0 + sar;
  unsigned int* aH = (unsigned int*)sAh;
  unsigned int* aL = (unsigned int*)sAl;
  f32x4 acc[4] = {};
  for (int k0 = 0; k0 < HH; k0 += 32) {
    {
      const float* ap = Hout + (long)(row0 + sar) * HH + k0 + sak;
      float4 v0 = *(const float4*)ap;
      float4 v1 = *(const float4*)(ap + 4);
      float vv[8] = {v0.x, v0.y, v0.z, v0.w, v1.x, v1.y, v1.z, v1.w};
#pragma unroll
      for (int i = 0; i < 4; i++) {
        unsigned int h0 = __float_as_uint(vv[2 * i]) >> 16, h1 = __float_as_uint(vv[2 * i + 1]) >> 16;
        float r0 = vv[2 * i] - __uint_as_float(h0 << 16), r1 = vv[2 * i + 1] - __uint_as_float(h1 << 16);
        unsigned int l0 = __float_as_uint(r0) >> 16, l1 = __float_as_uint(r1) >> 16;
        aH[sar * 20 + (sak >> 1) + i] = h0 | (h1 << 16);
        aL[sar * 20 + (sak >> 1) + i] = l0 | (l1 << 16);
      }
    }
    {
      long go = (long)np * HH + k0 + sak;
      *(uint4*)(sBh + sar * 40 + sak) = *(const uint4*)(Wsh + go);
      *(uint4*)(sBl + sar * 40 + sak) = *(const uint4*)(Wsl + go);
    }
    __syncthreads();
    bf16x8 ah = *(const bf16x8*)(sAh + (wm + l15) * 40 + quad * 8);
    bf16x8 al = *(const bf16x8*)(sAl + (wm + l15) * 40 + quad * 8);
#pragma unroll
    for (int ct = 0; ct < 4; ct++) {
      bf16x8 bh = *(const bf16x8*)(sBh + (ct * 16 + l15) * 40 + quad * 8);
      bf16x8 bl = *(const bf16x8*)(sBl + (ct * 16 + l15) * 40 + quad * 8);
      acc[ct] = __builtin_amdgcn_mfma_f32_16x16x32_bf16(al, bh, acc[ct], 0, 0, 0);
      acc[ct] = __builtin_amdgcn_mfma_f32_16x16x32_bf16(ah, bl, acc[ct], 0, 0, 0);
      acc[ct] = __builtin_amdgcn_mfma_f32_16x16x32_bf16(ah, bh, acc[ct], 0, 0, 0);
    }
    __syncthreads();
  }
#pragma unroll
  for (int ct = 0; ct < 4; ct++) {
    int col = ct * 16 + l15;
    int f = f0 + (col & 31);
    int fcol = (col < 32) ? f : NF + f;
    float bv = (f < NF) ? bias[fcol] : 0.f;
#pragma unroll
    for (int rg = 0; rg < 4; rg++) Cs[wm + quad * 4 + rg][col] = acc[ct][rg] + bv;
  }
  __syncthreads();
  {
    int fl = tid & 31, r8 = tid >> 5;
    int f = f0 + fl;
#pragma unroll
    for (int i = 0; i < 8; i++) {
      int rl = r8 * 8 + i;
      int rr = row0 + rl;
      float rm = Cs[rl][fl], im = Cs[rl][32 + fl];
      float sr = 0.f, si = 0.f;
      if (f < NF) { sr = S[(long)rr * DD + f]; si = S[(long)rr * DD + NF + f]; }
      SR[rl][fl] = rm * sr - im * si;
      SI[rl][fl] = rm * si + im * sr;
    }
  }
  __syncthreads();
  {
    int tl = tid & 63, fq = tid >> 6;
    int rr = row0 + tl;
    int n = rr / TT, t = rr - n * TT;
    int b = n >> 3, c = n & 7;
#pragma unroll
    for (int i = 0; i < 8; i++) {
      int fl = fq * 8 + i;
      int f = f0 + fl;
      if (f < NF) {
        long addr = ((((long)b * NF + f) * 8 + c) * 2) * TT + t;
        MS[addr] = SR[tl][fl];
        MS[addr + TT] = SI[tl][fl];
      }
    }
  }
}

// ---------------- PSD: one block per (b,f) ----------------
__launch_bounds__(256)
__global__ void k_psd(const float* __restrict__ MS, float* __restrict__ PSD) {
  __shared__ float buf[9616];
  __shared__ float part[64][8];
  const int tid = threadIdx.x;
  const long base = (long)blockIdx.x * 9616;
  for (int i = tid; i < 9616; i += 256) buf[i] = MS[base + i];
  __syncthreads();
  int p = tid & 63, q = tid >> 6;
  int c = p >> 3, e = p & 7;
  const float* xc = &buf[c * 1202];
  const float* xe = &buf[e * 1202];
  int t0 = q * 150, t1 = (q == 3) ? TT : t0 + 150;
  float ar = 0.f, ai = 0.f;
  for (int t = t0; t < t1; t++) {
    float cr = xc[t], ci = xc[TT + t];
    float er = xe[t], ei = xe[TT + t];
    ar += cr * er + ci * ei;
    ai += ci * er - cr * ei;
  }
  part[p][q * 2] = ar; part[p][q * 2 + 1] = ai;
  __syncthreads();
  if (tid < 64) {
    float sr = part[tid][0] + part[tid][2] + part[tid][4] + part[tid][6];
    float si = part[tid][1] + part[tid][3] + part[tid][5] + part[tid][7];
    PSD[((long)blockIdx.x * 64 + tid) * 2]     = sr * (1.f / 601.f);
    PSD[((long)blockIdx.x * 64 + tid) * 2 + 1] = si * (1.f / 601.f);
  }
}

// ---------------- 8x8 complex solve + MVDR weight ----------------
__launch_bounds__(64)
__global__ void k_solve(const float* __restrict__ PS, const float* __restrict__ PN,
                        float* __restrict__ WV) {
  int idx = blockIdx.x * 64 + threadIdx.x;
  if (idx >= NB * NF) return;
  float Ar[8][8], Ai[8][8], Br[8][8], Bi[8][8];
  const float* pn = PN + (long)idx * 128;
  const float* ps = PS + (long)idx * 128;
  for (int i = 0; i < 8; i++)
    for (int j = 0; j < 8; j++) {
      Ar[i][j] = pn[(i * 8 + j) * 2]; Ai[i][j] = pn[(i * 8 + j) * 2 + 1];
      Br[i][j] = ps[(i * 8 + j) * 2]; Bi[i][j] = ps[(i * 8 + j) * 2 + 1];
    }
  float tr = 0.f;
  for (int i = 0; i < 8; i++) tr += Ar[i][i];
  float load = 1e-6f * tr / 8.f + 1e-8f;
  for (int i = 0; i < 8; i++) Ar[i][i] += load;
  for (int k = 0; k < 8; k++) {
    int piv = k; float mx = Ar[k][k] * Ar[k][k] + Ai[k][k] * Ai[k][k];
    for (int i = k + 1; i < 8; i++) {
      float m2 = Ar[i][k] * Ar[i][k] + Ai[i][k] * Ai[i][k];
      if (m2 > mx) { mx = m2; piv = i; }
    }
    if (piv != k) {
      for (int j = 0; j < 8; j++) {
        float t0;
        t0 = Ar[k][j]; Ar[k][j] = Ar[piv][j]; Ar[piv][j] = t0;
        t0 = Ai[k][j]; Ai[k][j] = Ai[piv][j]; Ai[piv][j] = t0;
        t0 = Br[k][j]; Br[k][j] = Br[piv][j]; Br[piv][j] = t0;
        t0 = Bi[k][j]; Bi[k][j] = Bi[piv][j]; Bi[piv][j] = t0;
      }
    }
    float dr = Ar[k][k], di = Ai[k][k];
    float inv = 1.f / (dr * dr + di * di);
    float irr = dr * inv, iii = -di * inv;
    for (int j = 0; j < 8; j++) {
      float xr = Ar[k][j], xi = Ai[k][j];
      Ar[k][j] = xr * irr - xi * iii; Ai[k][j] = xr * iii + xi * irr;
      xr = Br[k][j]; xi = Bi[k][j];
      Br[k][j] = xr * irr - xi * iii; Bi[k][j] = xr * iii + xi * irr;
    }
    for (int i = 0; i < 8; i++) {
      if (i == k) continue;
      float fr = Ar[i][k], fi = Ai[i][k];
      for (int j = 0; j < 8; j++) {
        float kr = Ar[k][j], ki = Ai[k][j];
        Ar[i][j] -= fr * kr - fi * ki;
        Ai[i][j] -= fr * ki + fi * kr;
        kr = Br[k][j]; ki = Bi[k][j];
        Br[i][j] -= fr * kr - fi * ki;
        Bi[i][j] -= fr * ki + fi * kr;
      }
    }
  }
  float trr = 1e-8f, tri = 0.f;
  for (int i = 0; i < 8; i++) { trr += Br[i][i]; tri += Bi[i][i]; }
  float inv = 1.f / (trr * trr + tri * tri);
  for (int c = 0; c < 8; c++) {
    float xr = Br[c][0], xi = Bi[c][0];
    WV[((long)idx * 8 + c) * 2]     = (xr * trr + xi * tri) * inv;
    WV[((long)idx * 8 + c) * 2 + 1] = (xi * trr - xr * tri) * inv;
  }
}

// ---------------- beamform ----------------
__launch_bounds__(320)
__global__ void k_beam(const float* __restrict__ S, const float* __restrict__ WV,
                       float* __restrict__ ENH) {
  __shared__ float WL[NF * 16];
  int bb = blockIdx.x / TT, t = blockIdx.x - bb * TT;
  for (int i = threadIdx.x; i < NF * 16; i += 320) WL[i] = WV[(long)bb * NF * 16 + i];
  __syncthreads();
  int f = threadIdx.x;
  if (f >= NF) return;
  float er = 0.f, ei = 0.f;
#pragma unroll
  for (int c = 0; c < 8; c++) {
    float wr = WL[(f * 8 + c) * 2], wi = WL[(f * 8 + c) * 2 + 1];
    const float* srow = S + (((long)(bb * 8 + c) * TT) + t) * DD;
    float sr = srow[f], si = srow[NF + f];
    er += wr * sr + wi * si;
    ei += wr * si - wi * sr;
  }
  float* erow = ENH + ((long)bb * TT + t) * DD;
  erow[f] = er;
  erow[NF + f] = ei;
}

// ---------------- overlap-add + normalize + crop ----------------
__global__ void k_ola(const float* __restrict__ IFR, const float* __restrict__ WSQ,
                      float* __restrict__ out) {
  int idx = blockIdx.x * 256 + threadIdx.x;
  if (idx >= NB * LSEQ) return;
  int b = idx / LSEQ, l = idx - b * LSEQ;
  int p = l + FPAD;
  int t0 = (p <= 511) ? 0 : (p - 352) / 160;
  int t1 = p / 160; if (t1 > 600) t1 = 600;
  float s = 0.f;
  for (int t = t0; t <= t1; t++) s += IFR[((long)b * TT + t) * NFFT + (p - t * HOP)];
  out[idx] = s / fmaxf(WSQ[p], 1e-11f);
}

// ---------------- driver ----------------
extern "C" void kernel_launch(void* const* d_in, const int* in_sizes, int n_in,
                              void* d_out, int out_size, void* d_ws, size_t ws_size,
                              hipStream_t stream) {
  (void)in_sizes; (void)n_in; (void)out_size; (void)ws_size;
  const float* x   = (const float*)d_in[0];
  const float* Wih = (const float*)d_in[1];
  const float* Whh = (const float*)d_in[2];
  const float* bih = (const float*)d_in[3];
  const float* bhh = (const float*)d_in[4];
  const float* W1  = (const float*)d_in[5];
  const float* b1  = (const float*)d_in[6];
  const float* W2  = (const float*)d_in[7];
  const float* b2  = (const float*)d_in[8];
  float* ws = (float*)d_ws;

  float* XP    = ws + 0;          // 6,176,768 (later IFR)
  float* S     = ws + 6176768;    // 19,774,496
  float* XWM   = ws + 25951264;   // 19,774,496 (XW then MS; WF in tail)
  float* HOUT  = ws + 45725760;   // 4,924,288 (later ENH)
  float* PSD_S = ws + 50650048;   // 263,168
  float* PSD_N = ws + 50913216;   // 263,168
  float* WV    = ws + 51176384;   // 32,896
  float* BSUM  = ws + 51209280;   // 512
  float* WSQ   = ws + 51209792;   // 96,512 -> 51,306,304
  unsigned short* W1sh = (unsigned short*)(ws + 51306304);
  unsigned short* W1sl = (unsigned short*)(ws + 51347264);
  unsigned short* W2sh = (unsigned short*)(ws + 51388224);
  unsigned short* W2sl = (unsigned short*)(ws + 51429184); // -> 51,470,144
  unsigned short* BFth = (unsigned short*)(ws + 51470144);
  unsigned short* BFtl = (unsigned short*)(ws + 51644224);
  unsigned short* WTth = (unsigned short*)(ws + 51818304);
  unsigned short* WTtl = (unsigned short*)(ws + 51957568);
  unsigned short* BIth = (unsigned short*)(ws + 52096832);
  unsigned short* BItl = (unsigned short*)(ws + 52236096); // -> end 52,375,360 (~199.8MB)
  float* MS    = XWM;
  float* ENH   = HOUT;
  float* IFR   = XP;
  unsigned int* WF = (unsigned int*)(XWM + 19693568);   // after true end of XW; MS clobbers post-lstm

  k_wsq<<<(XPLEN + 255) / 256, 256, 0, stream>>>(WSQ);
  k_bfsplit<<<(640 * KPAD + 255) / 256, 256, 0, stream>>>(BFth, BFtl);
  k_wtsplit<<<(G4 * KPAD + 255) / 256, 256, 0, stream>>>(Wih, WTth, WTtl);
  k_bisplit<<<(NFFT * KPAD + 255) / 256, 256, 0, stream>>>(BIth, BItl);
  k_bsum<<<2, 256, 0, stream>>>(bih, bhh, BSUM);
  k_wmsplit<<<(2 * 640 * HH + 255) / 256, 256, 0, stream>>>(W1, W2, W1sh, W1sl, W2sh, W2sl);
  k_wfrag<<<128, 256, 0, stream>>>(Whh, WF);
  k_xp<<<(NSEQ * XPLEN + 255) / 256, 256, 0, stream>>>(x, XP);

  // STFT: S[38464,514] = frames(XP) @ BF
  {
    dim3 g(5, 301);
    k_gemm3<1><<<g, 256, 0, stream>>>(XP, BFth, BFtl, nullptr, S, NROWS, DD, NFFT, 0, DD);
  }
  // xW: XWM[38464,512] = S @ Wih^T + bsum
  {
    dim3 g(4, 301);
    k_gemm3<0><<<g, 256, 0, stream>>>(S, WTth, WTtl, BSUM, XWM, NROWS, G4, DD, DD, G4);
  }

  k_lstm<<<8, 512, 0, stream>>>(XWM, WF, HOUT);

  dim3 gm(9, 601);
  k_maskms<<<gm, 256, 0, stream>>>(HOUT, W1sh, W1sl, b1, S, MS);
  k_psd<<<NB * NF, 256, 0, stream>>>(MS, PSD_S);
  k_maskms<<<gm, 256, 0, stream>>>(HOUT, W2sh, W2sl, b2, S, MS);
  k_psd<<<NB * NF, 256, 0, stream>>>(MS, PSD_N);

  k_solve<<<(NB * NF + 63) / 64, 64, 0, stream>>>(PSD_S, PSD_N, WV);
  k_beam<<<NB * TT, 320, 0, stream>>>(S, WV, ENH);

  // iSTFT: IFR[4808,512] = ENH @ BI
  {
    dim3 g(4, 38);
    k_gemm3<0><<<g, 256, 0, stream>>>(ENH, BIth, BItl, nullptr, IFR, NB * TT, NFFT, DD, DD, NFFT);
  }

  k_ola<<<(NB * LSEQ + 255) / 256, 256, 0, stream>>>(IFR, WSQ, (float*)d_out);
}

// Round 13
// 1398.875 us; speedup vs baseline: 1.3309x; 1.3309x over previous
//
#include <hip/hip_runtime.h>
#include <math.h>

#define NFFT  512
#define WINL  320
#define HOP   160
#define FPAD  256
#define NF    257
#define TT    601
#define LSEQ  96000
#define XPLEN 96512
#define NCH   8
#define NB    8
#define NSEQ  64
#define NROWS 38464   // NSEQ*TT
#define DD    514
#define HH    128
#define G4    512
#define KPAD  544     // 17*32, zero-padded K for split-B arrays

typedef _Float16 h2v __attribute__((ext_vector_type(2)));
typedef short bf16x8 __attribute__((ext_vector_type(8)));
typedef float f32x4 __attribute__((ext_vector_type(4)));

// ---------------- init helpers ----------------
__device__ __forceinline__ float winval(int k) {
  if (k < 96 || k >= 416) return 0.f;
  return 0.5f - 0.5f * cosf((float)(2.0 * M_PI / 320.0) * (float)(k - 96));
}

__device__ __forceinline__ void split_bf16(float v, unsigned short* h, unsigned short* l) {
  unsigned int hb = __float_as_uint(v) >> 16;
  float r = v - __uint_as_float(hb << 16);
  *h = (unsigned short)hb;
  *l = (unsigned short)(__float_as_uint(r) >> 16);
}

__global__ void k_wsq(float* __restrict__ wsq) {
  int p = blockIdx.x * 256 + threadIdx.x;
  if (p >= XPLEN) return;
  int t0 = (p <= 511) ? 0 : (p - 352) / 160;
  int t1 = p / 160; if (t1 > 600) t1 = 600;
  float s = 0.f;
  for (int t = t0; t <= t1; t++) { float w = winval(p - t * HOP); s += w * w; }
  wsq[p] = s;
}

// BF split: Bt[n][k] = DFT-forward[k][n]
__global__ void k_bfsplit(unsigned short* __restrict__ H, unsigned short* __restrict__ L) {
  int idx = blockIdx.x * 256 + threadIdx.x;
  if (idx >= 640 * KPAD) return;
  int n = idx / KPAD, k = idx - n * KPAD;
  float v = 0.f;
  if (n < DD && k < NFFT) {
    float w = winval(k);
    int f = (n < NF) ? n : n - NF;
    int m = (k * f) & 511;
    float th = (float)(M_PI / 256.0) * (float)m;
    v = ((n < NF) ? cosf(th) : -sinf(th)) * w;
  }
  split_bf16(v, &H[idx], &L[idx]);
}

// WT split: Bt[n][k] = Wih[n][k]
__global__ void k_wtsplit(const float* __restrict__ Wih, unsigned short* __restrict__ H,
                          unsigned short* __restrict__ L) {
  int idx = blockIdx.x * 256 + threadIdx.x;
  if (idx >= G4 * KPAD) return;
  int n = idx / KPAD, k = idx - n * KPAD;
  float v = (k < DD) ? Wih[n * DD + k] : 0.f;
  split_bf16(v, &H[idx], &L[idx]);
}

// BI split: Bt[n][kk] = BI[kk][n]
__global__ void k_bisplit(unsigned short* __restrict__ H, unsigned short* __restrict__ L) {
  int idx = blockIdx.x * 256 + threadIdx.x;
  if (idx >= NFFT * KPAD) return;
  int n = idx / KPAD, kk = idx - n * KPAD;
  float v = 0.f;
  if (kk < DD) {
    float w = winval(n);
    int f = (kk < NF) ? kk : kk - NF;
    int edge = (f == 0 || f == 256);
    float alpha = edge ? 1.f : 2.f;
    int m = (n * f) & 511;
    float th = (float)(M_PI / 256.0) * (float)m;
    float c;
    if (kk < NF) c = alpha * cosf(th);
    else         c = edge ? 0.f : -alpha * sinf(th);
    v = c * w * (1.f / 512.f);
  }
  split_bf16(v, &H[idx], &L[idx]);
}

__global__ void k_bsum(const float* __restrict__ bih, const float* __restrict__ bhh,
                       float* __restrict__ BSUM) {
  int idx = blockIdx.x * 256 + threadIdx.x;
  if (idx < G4) BSUM[idx] = bih[idx] + bhh[idx];
}

// W1/W2 mask-weight split: Ws[n'][k], n' = ri*320 + f (ri=0 real, 1 imag), k<128
__global__ void k_wmsplit(const float* __restrict__ W1, const float* __restrict__ W2,
                          unsigned short* __restrict__ W1h, unsigned short* __restrict__ W1l,
                          unsigned short* __restrict__ W2h, unsigned short* __restrict__ W2l) {
  int idx = blockIdx.x * 256 + threadIdx.x;
  if (idx >= 2 * 640 * HH) return;
  int m = idx / (640 * HH);
  int rem = idx - m * 640 * HH;
  int np = rem / HH, k = rem - np * HH;
  int ri = np / 320, f = np - ri * 320;
  float v = 0.f;
  if (f < NF) {
    int fcol = (ri == 0) ? f : NF + f;
    v = (m == 0) ? W1[fcol * HH + k] : W2[fcol * HH + k];
  }
  unsigned short h, l;
  split_bf16(v, &h, &l);
  if (m == 0) { W1h[rem] = h; W1l[rem] = l; }
  else        { W2h[rem] = h; W2l[rem] = l; }
}

// pack Whh into f16 pairs, uint4-transposed (r10 layout):
// thread j reads uint4 at (i4*512 + j): lane-coalesced AND 16B-vectorized.
__global__ void k_wpack(const float* __restrict__ Whh, unsigned int* __restrict__ WhhP4) {
  int idx = blockIdx.x * 256 + threadIdx.x;
  if (idx >= G4 * 64) return;
  int j = idx >> 6, k2 = idx & 63;
  _Float16 lo = (_Float16)Whh[j * HH + 2 * k2];
  _Float16 hi = (_Float16)Whh[j * HH + 2 * k2 + 1];
  unsigned int u = ((unsigned int)__builtin_bit_cast(unsigned short, hi) << 16)
                 |  (unsigned int)__builtin_bit_cast(unsigned short, lo);
  WhhP4[(k2 >> 2) * (G4 * 4) + j * 4 + (k2 & 3)] = u;
}

// reflect-padded multichannel extraction: XP[n][i], n=b*8+c
__global__ void k_xp(const float* __restrict__ x, float* __restrict__ XP) {
  int idx = blockIdx.x * 256 + threadIdx.x;
  if (idx >= NSEQ * XPLEN) return;
  int n = idx / XPLEN, i = idx - n * XPLEN;
  int j = i - FPAD;
  if (j < 0) j = -j;
  else if (j >= LSEQ) j = 2 * LSEQ - 2 - j;
  int b = n >> 3, c = n & 7;
  XP[idx] = x[((long)b * LSEQ + j) * NCH + c];
}

// ---------------- split-bf16 MFMA GEMM: C[M,N] = A[M,K] * Bt^T (+bias) ----------------
template <int GATHER>
__launch_bounds__(256)
__global__ void k_gemm3(const float* __restrict__ A,
                        const unsigned short* __restrict__ Bth,
                        const unsigned short* __restrict__ Btl,
                        const float* __restrict__ bias, float* __restrict__ C,
                        int M, int N, int K, int lda, int ldc) {
  __shared__ __align__(16) unsigned short sAh[128 * 40];
  __shared__ __align__(16) unsigned short sAl[128 * 40];
  __shared__ __align__(16) unsigned short sBh[128 * 40];
  __shared__ __align__(16) unsigned short sBl[128 * 40];
  const int tid = threadIdx.x;
  const int row0 = blockIdx.y * 128, col0 = blockIdx.x * 128;
  const int sar = tid >> 1, sak = (tid & 1) * 16;
  const int arow = row0 + sar;
  long abase;
  if (GATHER) { int nn = arow / TT; int t = arow - nn * TT; abase = (long)nn * XPLEN + (long)t * HOP; }
  else        { abase = (long)arow * lda; }
  const bool arok = (arow < M);
  const int lane = tid & 63, w = tid >> 6;
  const int wm = (w >> 1) * 64, wn = (w & 1) * 64;
  const int l15 = lane & 15, quad = lane >> 4;
  f32x4 acc[4][4] = {};
  unsigned int* aH = (unsigned int*)sAh;
  unsigned int* aL = (unsigned int*)sAl;
  uint4* bH = (uint4*)sBh;
  uint4* bL = (uint4*)sBl;
  for (int k0 = 0; k0 < K; k0 += 32) {
#pragma unroll
    for (int i = 0; i < 8; i++) {
      int kk = k0 + sak + 2 * i;
      float v0 = 0.f, v1 = 0.f;
      if (arok) {
        if (kk + 1 < K) { float2 t2 = *(const float2*)(A + abase + kk); v0 = t2.x; v1 = t2.y; }
        else if (kk < K) { v0 = A[abase + kk]; }
      }
      unsigned int h0 = __float_as_uint(v0) >> 16, h1 = __float_as_uint(v1) >> 16;
      float r0 = v0 - __uint_as_float(h0 << 16), r1 = v1 - __uint_as_float(h1 << 16);
      unsigned int l0 = __float_as_uint(r0) >> 16, l1 = __float_as_uint(r1) >> 16;
      aH[sar * 20 + (sak >> 1) + i] = h0 | (h1 << 16);
      aL[sar * 20 + (sak >> 1) + i] = l0 | (l1 << 16);
    }
#pragma unroll
    for (int h = 0; h < 2; h++) {
      int idx = tid + h * 256;
      int r = idx >> 2, c = idx & 3;
      long go = (long)(col0 + r) * KPAD + k0 + c * 8;
      bH[r * 5 + c] = *(const uint4*)(Bth + go);
      bL[r * 5 + c] = *(const uint4*)(Btl + go);
    }
    __syncthreads();
    bf16x8 ah[4], al[4], bh[4], bl[4];
#pragma unroll
    for (int i = 0; i < 4; i++) {
      int off = (wm + i * 16 + l15) * 40 + quad * 8;
      ah[i] = *(const bf16x8*)(sAh + off);
      al[i] = *(const bf16x8*)(sAl + off);
      int boff = (wn + i * 16 + l15) * 40 + quad * 8;
      bh[i] = *(const bf16x8*)(sBh + boff);
      bl[i] = *(const bf16x8*)(sBl + boff);
    }
#pragma unroll
    for (int i = 0; i < 4; i++)
#pragma unroll
      for (int j = 0; j < 4; j++) {
        acc[i][j] = __builtin_amdgcn_mfma_f32_16x16x32_bf16(al[i], bh[j], acc[i][j], 0, 0, 0);
        acc[i][j] = __builtin_amdgcn_mfma_f32_16x16x32_bf16(ah[i], bl[j], acc[i][j], 0, 0, 0);
        acc[i][j] = __builtin_amdgcn_mfma_f32_16x16x32_bf16(ah[i], bh[j], acc[i][j], 0, 0, 0);
      }
    __syncthreads();
  }
#pragma unroll
  for (int i = 0; i < 4; i++)
#pragma unroll
    for (int j = 0; j < 4; j++) {
      int cc = col0 + wn + j * 16 + l15;
      if (cc >= N) continue;
      float bv = bias ? bias[cc] : 0.f;
#pragma unroll
      for (int rg = 0; rg < 4; rg++) {
        int rr = row0 + wm + i * 16 + quad * 4 + rg;
        if (rr < M) C[(long)rr * ldc + cc] = acc[i][j][rg] + bv;
      }
    }
}

// ---------------- LSTM v8 (r10, structural plateau ~500us): coalesced refetch + dot2 ----------------
// dot2 floor: 256 MAC/cyc/CU VALU ceiling + 2 mandatory all-to-all barriers/step.
// MFMA variant (r12) was latency-bound at 8 blocks (940us) -> reverted.
__device__ __forceinline__ float tanh_fast(float x) {
  float e = __expf(2.f * x);
  return 1.f - 2.f / (e + 1.f);
}

__launch_bounds__(512, 2)
__global__ void k_lstm(const float* __restrict__ XW, const unsigned int* __restrict__ WhhP4,
                       float* __restrict__ Hout) {
  __shared__ unsigned int hl2[64];   // h packed as 64 f16-pairs
  __shared__ float gl[G4];
  const int j = threadIdx.x;
  const int n = blockIdx.x;
  const uint4* W4 = (const uint4*)WhhP4;
  unsigned int wp[64];
#pragma unroll
  for (int i4 = 0; i4 < 16; i4++) {
    uint4 v = W4[i4 * G4 + j];
    wp[4 * i4]     = v.x;
    wp[4 * i4 + 1] = v.y;
    wp[4 * i4 + 2] = v.z;
    wp[4 * i4 + 3] = v.w;
  }
  float cst = 0.f;
  if (j < 64) hl2[j] = 0u;
  const float* xwrow = XW + (long)n * TT * G4 + j;
  const int lane = j & 63;
  float xnext = xwrow[0];
  __syncthreads();
  for (int t = 0; t < TT; t++) {
    float xv = xnext;
    if (t + 1 < TT) xnext = xwrow[(t + 1) * G4];
    unsigned int vh = hl2[lane];
    float a0 = 0.f, a1 = 0.f, a2 = 0.f, a3 = 0.f;
#pragma unroll
    for (int q = 0; q < 16; q++) {
      unsigned int p0 = __builtin_amdgcn_readlane(vh, 4 * q);
      unsigned int p1 = __builtin_amdgcn_readlane(vh, 4 * q + 1);
      unsigned int p2 = __builtin_amdgcn_readlane(vh, 4 * q + 2);
      unsigned int p3 = __builtin_amdgcn_readlane(vh, 4 * q + 3);
      a0 = __builtin_amdgcn_fdot2(__builtin_bit_cast(h2v, p0), __builtin_bit_cast(h2v, wp[4 * q]),     a0, false);
      a1 = __builtin_amdgcn_fdot2(__builtin_bit_cast(h2v, p1), __builtin_bit_cast(h2v, wp[4 * q + 1]), a1, false);
      a2 = __builtin_amdgcn_fdot2(__builtin_bit_cast(h2v, p2), __builtin_bit_cast(h2v, wp[4 * q + 2]), a2, false);
      a3 = __builtin_amdgcn_fdot2(__builtin_bit_cast(h2v, p3), __builtin_bit_cast(h2v, wp[4 * q + 3]), a3, false);
    }
    gl[j] = ((a0 + a1) + (a2 + a3)) + xv;
    __syncthreads();
    if (j < HH) {
      float gi = gl[j], gf = gl[HH + j], gg = gl[2 * HH + j], go = gl[3 * HH + j];
      float si = 1.f / (1.f + __expf(-gi));
      float sf = 1.f / (1.f + __expf(-gf));
      float so = 1.f / (1.f + __expf(-go));
      cst = sf * cst + si * tanh_fast(gg);
      float hv = so * tanh_fast(cst);
      ((_Float16*)hl2)[j] = (_Float16)hv;
      Hout[((long)n * TT + t) * HH + j] = hv;
    }
    __syncthreads();
  }
}

// ---------------- mask GEMM (split-bf16 MFMA) + mask apply + transpose ----------------
// MS layout (r13): [b][f][c][t] complex-interleaved (re,im) pairs: offset
// (((b*NF+f)*8+c)*601 + t)*2 + ri -> phase-B writes are coalesced float2 stores,
// and k_psd reads (re,im) with one ds_read_b64.
__launch_bounds__(256)
__global__ void k_maskms(const float* __restrict__ Hout,
                         const unsigned short* __restrict__ Wsh,
                         const unsigned short* __restrict__ Wsl,
                         const float* __restrict__ bias, const float* __restrict__ S,
                         float* __restrict__ MS) {
  __shared__ __align__(16) unsigned short sAh[64 * 40];
  __shared__ __align__(16) unsigned short sAl[64 * 40];
  __shared__ __align__(16) unsigned short sBh[64 * 40];
  __shared__ __align__(16) unsigned short sBl[64 * 40];
  __shared__ float Cs[64][68];
  __shared__ float SR[64][33];
  __shared__ float SI[64][33];
  const int tid = threadIdx.x;
  const int f0 = blockIdx.x * 32;
  const int row0 = blockIdx.y * 64;
  const int lane = tid & 63, w = tid >> 6;
  const int wm = w * 16;
  const int l15 = lane & 15, quad = lane >> 4;
  const int sar = tid >> 2;
  const int sak = (tid & 3) * 8;
  const int np = ((sar < 32) ? 0 : 320 - 32) + f0 + sar;
  unsigned int* aH = (unsigned int*)sAh;
  unsigned int* aL = (unsigned int*)sAl;
  f32x4 acc[4] = {};
  for (int k0 = 0; k0 < HH; k0 += 32) {
    {
      const float* ap = Hout + (long)(row0 + sar) * HH + k0 + sak;
      float4 v0 = *(const float4*)ap;
      float4 v1 = *(const float4*)(ap + 4);
      float vv[8] = {v0.x, v0.y, v0.z, v0.w, v1.x, v1.y, v1.z, v1.w};
#pragma unroll
      for (int i = 0; i < 4; i++) {
        unsigned int h0 = __float_as_uint(vv[2 * i]) >> 16, h1 = __float_as_uint(vv[2 * i + 1]) >> 16;
        float r0 = vv[2 * i] - __uint_as_float(h0 << 16), r1 = vv[2 * i + 1] - __uint_as_float(h1 << 16);
        unsigned int l0 = __float_as_uint(r0) >> 16, l1 = __float_as_uint(r1) >> 16;
        aH[sar * 20 + (sak >> 1) + i] = h0 | (h1 << 16);
        aL[sar * 20 + (sak >> 1) + i] = l0 | (l1 << 16);
      }
    }
    {
      long go = (long)np * HH + k0 + sak;
      *(uint4*)(sBh + sar * 40 + sak) = *(const uint4*)(Wsh + go);
      *(uint4*)(sBl + sar * 40 + sak) = *(const uint4*)(Wsl + go);
    }
    __syncthreads();
    bf16x8 ah = *(const bf16x8*)(sAh + (wm + l15) * 40 + quad * 8);
    bf16x8 al = *(const bf16x8*)(sAl + (wm + l15) * 40 + quad * 8);
#pragma unroll
    for (int ct = 0; ct < 4; ct++) {
      bf16x8 bh = *(const bf16x8*)(sBh + (ct * 16 + l15) * 40 + quad * 8);
      bf16x8 bl = *(const bf16x8*)(sBl + (ct * 16 + l15) * 40 + quad * 8);
      acc[ct] = __builtin_amdgcn_mfma_f32_16x16x32_bf16(al, bh, acc[ct], 0, 0, 0);
      acc[ct] = __builtin_amdgcn_mfma_f32_16x16x32_bf16(ah, bl, acc[ct], 0, 0, 0);
      acc[ct] = __builtin_amdgcn_mfma_f32_16x16x32_bf16(ah, bh, acc[ct], 0, 0, 0);
    }
    __syncthreads();
  }
#pragma unroll
  for (int ct = 0; ct < 4; ct++) {
    int col = ct * 16 + l15;
    int f = f0 + (col & 31);
    int fcol = (col < 32) ? f : NF + f;
    float bv = (f < NF) ? bias[fcol] : 0.f;
#pragma unroll
    for (int rg = 0; rg < 4; rg++) Cs[wm + quad * 4 + rg][col] = acc[ct][rg] + bv;
  }
  __syncthreads();
  {
    int fl = tid & 31, r8 = tid >> 5;
    int f = f0 + fl;
#pragma unroll
    for (int i = 0; i < 8; i++) {
      int rl = r8 * 8 + i;
      int rr = row0 + rl;
      float rm = Cs[rl][fl], im = Cs[rl][32 + fl];
      float sr = 0.f, si = 0.f;
      if (f < NF) { sr = S[(long)rr * DD + f]; si = S[(long)rr * DD + NF + f]; }
      SR[rl][fl] = rm * sr - im * si;
      SI[rl][fl] = rm * si + im * sr;
    }
  }
  __syncthreads();
  {
    int tl = tid & 63, fq = tid >> 6;
    int rr = row0 + tl;
    int n = rr / TT, t = rr - n * TT;
    int b = n >> 3, c = n & 7;
#pragma unroll
    for (int i = 0; i < 8; i++) {
      int fl = fq * 8 + i;
      int f = f0 + fl;
      if (f < NF) {
        long addr = ((((long)b * NF + f) * 8 + c) * (long)TT + t) * 2;
        *(float2*)&MS[addr] = make_float2(SR[tl][fl], SI[tl][fl]);
      }
    }
  }
}

// ---------------- PSD: one block per (b,f); complex-interleaved MS ----------------
__launch_bounds__(256)
__global__ void k_psd(const float* __restrict__ MS, float* __restrict__ PSD) {
  __shared__ float buf[9616];   // 8 ch * 601 * 2 (interleaved)
  __shared__ float part[64][8];
  const int tid = threadIdx.x;
  const long base = (long)blockIdx.x * 9616;
  for (int i = tid; i < 9616; i += 256) buf[i] = MS[base + i];
  __syncthreads();
  int p = tid & 63, q = tid >> 6;
  int c = p >> 3, e = p & 7;
  const float2* xc = (const float2*)&buf[c * 1202];
  const float2* xe = (const float2*)&buf[e * 1202];
  int t0 = q * 150, t1 = (q == 3) ? TT : t0 + 150;
  float ar = 0.f, ai = 0.f;
  for (int t = t0; t < t1; t++) {
    float2 m = xc[t];
    float2 v = xe[t];
    ar += m.x * v.x + m.y * v.y;
    ai += m.y * v.x - m.x * v.y;
  }
  part[p][q * 2] = ar; part[p][q * 2 + 1] = ai;
  __syncthreads();
  if (tid < 64) {
    float sr = part[tid][0] + part[tid][2] + part[tid][4] + part[tid][6];
    float si = part[tid][1] + part[tid][3] + part[tid][5] + part[tid][7];
    PSD[((long)blockIdx.x * 64 + tid) * 2]     = sr * (1.f / 601.f);
    PSD[((long)blockIdx.x * 64 + tid) * 2 + 1] = si * (1.f / 601.f);
  }
}

// ---------------- 8x8 complex solve + MVDR weight ----------------
__launch_bounds__(64)
__global__ void k_solve(const float* __restrict__ PS, const float* __restrict__ PN,
                        float* __restrict__ WV) {
  int idx = blockIdx.x * 64 + threadIdx.x;
  if (idx >= NB * NF) return;
  float Ar[8][8], Ai[8][8], Br[8][8], Bi[8][8];
  const float* pn = PN + (long)idx * 128;
  const float* ps = PS + (long)idx * 128;
  for (int i = 0; i < 8; i++)
    for (int j = 0; j < 8; j++) {
      Ar[i][j] = pn[(i * 8 + j) * 2]; Ai[i][j] = pn[(i * 8 + j) * 2 + 1];
      Br[i][j] = ps[(i * 8 + j) * 2]; Bi[i][j] = ps[(i * 8 + j) * 2 + 1];
    }
  float tr = 0.f;
  for (int i = 0; i < 8; i++) tr += Ar[i][i];
  float load = 1e-6f * tr / 8.f + 1e-8f;
  for (int i = 0; i < 8; i++) Ar[i][i] += load;
  for (int k = 0; k < 8; k++) {
    int piv = k; float mx = Ar[k][k] * Ar[k][k] + Ai[k][k] * Ai[k][k];
    for (int i = k + 1; i < 8; i++) {
      float m2 = Ar[i][k] * Ar[i][k] + Ai[i][k] * Ai[i][k];
      if (m2 > mx) { mx = m2; piv = i; }
    }
    if (piv != k) {
      for (int j = 0; j < 8; j++) {
        float t0;
        t0 = Ar[k][j]; Ar[k][j] = Ar[piv][j]; Ar[piv][j] = t0;
        t0 = Ai[k][j]; Ai[k][j] = Ai[piv][j]; Ai[piv][j] = t0;
        t0 = Br[k][j]; Br[k][j] = Br[piv][j]; Br[piv][j] = t0;
        t0 = Bi[k][j]; Bi[k][j] = Bi[piv][j]; Bi[piv][j] = t0;
      }
    }
    float dr = Ar[k][k], di = Ai[k][k];
    float inv = 1.f / (dr * dr + di * di);
    float irr = dr * inv, iii = -di * inv;
    for (int j = 0; j < 8; j++) {
      float xr = Ar[k][j], xi = Ai[k][j];
      Ar[k][j] = xr * irr - xi * iii; Ai[k][j] = xr * iii + xi * irr;
      xr = Br[k][j]; xi = Bi[k][j];
      Br[k][j] = xr * irr - xi * iii; Bi[k][j] = xr * iii + xi * irr;
    }
    for (int i = 0; i < 8; i++) {
      if (i == k) continue;
      float fr = Ar[i][k], fi = Ai[i][k];
      for (int j = 0; j < 8; j++) {
        float kr = Ar[k][j], ki = Ai[k][j];
        Ar[i][j] -= fr * kr - fi * ki;
        Ai[i][j] -= fr * ki + fi * kr;
        kr = Br[k][j]; ki = Bi[k][j];
        Br[i][j] -= fr * kr - fi * ki;
        Bi[i][j] -= fr * ki + fi * kr;
      }
    }
  }
  float trr = 1e-8f, tri = 0.f;
  for (int i = 0; i < 8; i++) { trr += Br[i][i]; tri += Bi[i][i]; }
  float inv = 1.f / (trr * trr + tri * tri);
  for (int c = 0; c < 8; c++) {
    float xr = Br[c][0], xi = Bi[c][0];
    WV[((long)idx * 8 + c) * 2]     = (xr * trr + xi * tri) * inv;
    WV[((long)idx * 8 + c) * 2 + 1] = (xi * trr - xr * tri) * inv;
  }
}

// ---------------- beamform ----------------
__launch_bounds__(320)
__global__ void k_beam(const float* __restrict__ S, const float* __restrict__ WV,
                       float* __restrict__ ENH) {
  __shared__ float WL[NF * 16];
  int bb = blockIdx.x / TT, t = blockIdx.x - bb * TT;
  for (int i = threadIdx.x; i < NF * 16; i += 320) WL[i] = WV[(long)bb * NF * 16 + i];
  __syncthreads();
  int f = threadIdx.x;
  if (f >= NF) return;
  float er = 0.f, ei = 0.f;
#pragma unroll
  for (int c = 0; c < 8; c++) {
    float wr = WL[(f * 8 + c) * 2], wi = WL[(f * 8 + c) * 2 + 1];
    const float* srow = S + (((long)(bb * 8 + c) * TT) + t) * DD;
    float sr = srow[f], si = srow[NF + f];
    er += wr * sr + wi * si;
    ei += wr * si - wi * sr;
  }
  float* erow = ENH + ((long)bb * TT + t) * DD;
  erow[f] = er;
  erow[NF + f] = ei;
}

// ---------------- overlap-add + normalize + crop ----------------
__global__ void k_ola(const float* __restrict__ IFR, const float* __restrict__ WSQ,
                      float* __restrict__ out) {
  int idx = blockIdx.x * 256 + threadIdx.x;
  if (idx >= NB * LSEQ) return;
  int b = idx / LSEQ, l = idx - b * LSEQ;
  int p = l + FPAD;
  int t0 = (p <= 511) ? 0 : (p - 352) / 160;
  int t1 = p / 160; if (t1 > 600) t1 = 600;
  float s = 0.f;
  for (int t = t0; t <= t1; t++) s += IFR[((long)b * TT + t) * NFFT + (p - t * HOP)];
  out[idx] = s / fmaxf(WSQ[p], 1e-11f);
}

// ---------------- driver ----------------
extern "C" void kernel_launch(void* const* d_in, const int* in_sizes, int n_in,
                              void* d_out, int out_size, void* d_ws, size_t ws_size,
                              hipStream_t stream) {
  (void)in_sizes; (void)n_in; (void)out_size; (void)ws_size;
  const float* x   = (const float*)d_in[0];
  const float* Wih = (const float*)d_in[1];
  const float* Whh = (const float*)d_in[2];
  const float* bih = (const float*)d_in[3];
  const float* bhh = (const float*)d_in[4];
  const float* W1  = (const float*)d_in[5];
  const float* b1  = (const float*)d_in[6];
  const float* W2  = (const float*)d_in[7];
  const float* b2  = (const float*)d_in[8];
  float* ws = (float*)d_ws;

  float* XP    = ws + 0;          // 6,176,768 (later IFR)
  float* S     = ws + 6176768;    // 19,774,496
  float* XWM   = ws + 25951264;   // 19,774,496 (XW then MS; WhhP4 in tail)
  float* HOUT  = ws + 45725760;   // 4,924,288 (later ENH)
  float* PSD_S = ws + 50650048;   // 263,168
  float* PSD_N = ws + 50913216;   // 263,168
  float* WV    = ws + 51176384;   // 32,896
  float* BSUM  = ws + 51209280;   // 512
  float* WSQ   = ws + 51209792;   // 96,512 -> 51,306,304
  unsigned short* W1sh = (unsigned short*)(ws + 51306304);
  unsigned short* W1sl = (unsigned short*)(ws + 51347264);
  unsigned short* W2sh = (unsigned short*)(ws + 51388224);
  unsigned short* W2sl = (unsigned short*)(ws + 51429184); // -> 51,470,144
  unsigned short* BFth = (unsigned short*)(ws + 51470144);
  unsigned short* BFtl = (unsigned short*)(ws + 51644224);
  unsigned short* WTth = (unsigned short*)(ws + 51818304);
  unsigned short* WTtl = (unsigned short*)(ws + 51957568);
  unsigned short* BIth = (unsigned short*)(ws + 52096832);
  unsigned short* BItl = (unsigned short*)(ws + 52236096); // -> end 52,375,360 (~199.8MB)
  float* MS    = XWM;
  float* ENH   = HOUT;
  float* IFR   = XP;
  unsigned int* WhhP4 = (unsigned int*)(XWM + 19693568);   // after true end of XW

  k_wsq<<<(XPLEN + 255) / 256, 256, 0, stream>>>(WSQ);
  k_bfsplit<<<(640 * KPAD + 255) / 256, 256, 0, stream>>>(BFth, BFtl);
  k_wtsplit<<<(G4 * KPAD + 255) / 256, 256, 0, stream>>>(Wih, WTth, WTtl);
  k_bisplit<<<(NFFT * KPAD + 255) / 256, 256, 0, stream>>>(BIth, BItl);
  k_bsum<<<2, 256, 0, stream>>>(bih, bhh, BSUM);
  k_wmsplit<<<(2 * 640 * HH + 255) / 256, 256, 0, stream>>>(W1, W2, W1sh, W1sl, W2sh, W2sl);
  k_wpack<<<(G4 * 64 + 255) / 256, 256, 0, stream>>>(Whh, WhhP4);
  k_xp<<<(NSEQ * XPLEN + 255) / 256, 256, 0, stream>>>(x, XP);

  // STFT: S[38464,514] = frames(XP) @ BF
  {
    dim3 g(5, 301);
    k_gemm3<1><<<g, 256, 0, stream>>>(XP, BFth, BFtl, nullptr, S, NROWS, DD, NFFT, 0, DD);
  }
  // xW: XWM[38464,512] = S @ Wih^T + bsum
  {
    dim3 g(4, 301);
    k_gemm3<0><<<g, 256, 0, stream>>>(S, WTth, WTtl, BSUM, XWM, NROWS, G4, DD, DD, G4);
  }

  k_lstm<<<64, 512, 0, stream>>>(XWM, WhhP4, HOUT);

  dim3 gm(9, 601);
  k_maskms<<<gm, 256, 0, stream>>>(HOUT, W1sh, W1sl, b1, S, MS);
  k_psd<<<NB * NF, 256, 0, stream>>>(MS, PSD_S);
  k_maskms<<<gm, 256, 0, stream>>>(HOUT, W2sh, W2sl, b2, S, MS);
  k_psd<<<NB * NF, 256, 0, stream>>>(MS, PSD_N);

  k_solve<<<(NB * NF + 63) / 64, 64, 0, stream>>>(PSD_S, PSD_N, WV);
  k_beam<<<NB * TT, 320, 0, stream>>>(S, WV, ENH);

  // iSTFT: IFR[4808,512] = ENH @ BI
  {
    dim3 g(4, 38);
    k_gemm3<0><<<g, 256, 0, stream>>>(ENH, BIth, BItl, nullptr, IFR, NB * TT, NFFT, DD, DD, NFFT);
  }

  k_ola<<<(NB * LSEQ + 255) / 256, 256, 0, stream>>>(IFR, WSQ, (float*)d_out);
}

// Round 14
// 1284.358 us; speedup vs baseline: 1.4496x; 1.0892x over previous
//
#include <hip/hip_runtime.h>
#include <math.h>

#define NFFT  512
#define WINL  320
#define HOP   160
#define FPAD  256
#define NF    257
#define TT    601
#define LSEQ  96000
#define XPLEN 96512
#define NCH   8
#define NB    8
#define NSEQ  64
#define NROWS 38464   // NSEQ*TT
#define DD    514
#define HH    128
#define G4    512
#define KPAD  544     // 17*32, zero-padded K for split-B arrays
#define NCOMB 1026    // 514 (S cols) + 512 (XW cols)

typedef _Float16 h2v __attribute__((ext_vector_type(2)));
typedef short bf16x8 __attribute__((ext_vector_type(8)));
typedef float f32x4 __attribute__((ext_vector_type(4)));

// ---------------- init helpers ----------------
__device__ __forceinline__ float winval(int k) {
  if (k < 96 || k >= 416) return 0.f;
  return 0.5f - 0.5f * cosf((float)(2.0 * M_PI / 320.0) * (float)(k - 96));
}

__device__ __forceinline__ void split_bf16(float v, unsigned short* h, unsigned short* l) {
  unsigned int hb = __float_as_uint(v) >> 16;
  float r = v - __uint_as_float(hb << 16);
  *h = (unsigned short)hb;
  *l = (unsigned short)(__float_as_uint(r) >> 16);
}

__global__ void k_wsq(float* __restrict__ wsq) {
  int p = blockIdx.x * 256 + threadIdx.x;
  if (p >= XPLEN) return;
  int t0 = (p <= 511) ? 0 : (p - 352) / 160;
  int t1 = p / 160; if (t1 > 600) t1 = 600;
  float s = 0.f;
  for (int t = t0; t <= t1; t++) { float w = winval(p - t * HOP); s += w * w; }
  wsq[p] = s;
}

// fp32 forward-DFT matrix BFf[k][d] (512 x 514), for the BW precompute GEMM
__global__ void k_bff(float* __restrict__ BFf) {
  int idx = blockIdx.x * 256 + threadIdx.x;
  if (idx >= NFFT * DD) return;
  int k = idx / DD, d = idx - k * DD;
  float w = winval(k);
  int f = (d < NF) ? d : d - NF;
  int m = (k * f) & 511;
  float th = (float)(M_PI / 256.0) * (float)m;
  BFf[idx] = ((d < NF) ? cosf(th) : -sinf(th)) * w;
}

// WT split: Bt[n][k] = Wih[n][k]  (used by the BW precompute)
__global__ void k_wtsplit(const float* __restrict__ Wih, unsigned short* __restrict__ H,
                          unsigned short* __restrict__ L) {
  int idx = blockIdx.x * 256 + threadIdx.x;
  if (idx >= G4 * KPAD) return;
  int n = idx / KPAD, k = idx - n * KPAD;
  float v = (k < DD) ? Wih[n * DD + k] : 0.f;
  split_bf16(v, &H[idx], &L[idx]);
}

// Combined split B for the fused STFT+xW GEMM: BC[n][k], n in [0,1152)
//   n < 514        : BF column n     (S output)
//   514 <= n <1026 : BW[k][n-514]    (XW output; BW = BF @ Wih^T, fp32 precomputed)
//   else           : 0
__global__ void k_bcomb(const float* __restrict__ BWf, unsigned short* __restrict__ H,
                        unsigned short* __restrict__ L) {
  int idx = blockIdx.x * 256 + threadIdx.x;
  if (idx >= 1152 * KPAD) return;
  int n = idx / KPAD, k = idx - n * KPAD;
  float v = 0.f;
  if (k < NFFT) {
    if (n < DD) {
      float w = winval(k);
      int f = (n < NF) ? n : n - NF;
      int m = (k * f) & 511;
      float th = (float)(M_PI / 256.0) * (float)m;
      v = ((n < NF) ? cosf(th) : -sinf(th)) * w;
    } else if (n < NCOMB) {
      v = BWf[k * G4 + (n - 514)];
    }
  }
  split_bf16(v, &H[idx], &L[idx]);
}

// BI split: Bt[n][kk] = BI[kk][n]
__global__ void k_bisplit(unsigned short* __restrict__ H, unsigned short* __restrict__ L) {
  int idx = blockIdx.x * 256 + threadIdx.x;
  if (idx >= NFFT * KPAD) return;
  int n = idx / KPAD, kk = idx - n * KPAD;
  float v = 0.f;
  if (kk < DD) {
    float w = winval(n);
    int f = (kk < NF) ? kk : kk - NF;
    int edge = (f == 0 || f == 256);
    float alpha = edge ? 1.f : 2.f;
    int m = (n * f) & 511;
    float th = (float)(M_PI / 256.0) * (float)m;
    float c;
    if (kk < NF) c = alpha * cosf(th);
    else         c = edge ? 0.f : -alpha * sinf(th);
    v = c * w * (1.f / 512.f);
  }
  split_bf16(v, &H[idx], &L[idx]);
}

__global__ void k_bsum(const float* __restrict__ bih, const float* __restrict__ bhh,
                       float* __restrict__ BSUM) {
  int idx = blockIdx.x * 256 + threadIdx.x;
  if (idx < G4) BSUM[idx] = bih[idx] + bhh[idx];
}

// W1/W2 mask-weight split: Ws[n'][k], n' = ri*320 + f
__global__ void k_wmsplit(const float* __restrict__ W1, const float* __restrict__ W2,
                          unsigned short* __restrict__ W1h, unsigned short* __restrict__ W1l,
                          unsigned short* __restrict__ W2h, unsigned short* __restrict__ W2l) {
  int idx = blockIdx.x * 256 + threadIdx.x;
  if (idx >= 2 * 640 * HH) return;
  int m = idx / (640 * HH);
  int rem = idx - m * 640 * HH;
  int np = rem / HH, k = rem - np * HH;
  int ri = np / 320, f = np - ri * 320;
  float v = 0.f;
  if (f < NF) {
    int fcol = (ri == 0) ? f : NF + f;
    v = (m == 0) ? W1[fcol * HH + k] : W2[fcol * HH + k];
  }
  unsigned short h, l;
  split_bf16(v, &h, &l);
  if (m == 0) { W1h[rem] = h; W1l[rem] = l; }
  else        { W2h[rem] = h; W2l[rem] = l; }
}

// pack Whh into f16 pairs, uint4-transposed (r10 layout)
__global__ void k_wpack(const float* __restrict__ Whh, unsigned int* __restrict__ WhhP4) {
  int idx = blockIdx.x * 256 + threadIdx.x;
  if (idx >= G4 * 64) return;
  int j = idx >> 6, k2 = idx & 63;
  _Float16 lo = (_Float16)Whh[j * HH + 2 * k2];
  _Float16 hi = (_Float16)Whh[j * HH + 2 * k2 + 1];
  unsigned int u = ((unsigned int)__builtin_bit_cast(unsigned short, hi) << 16)
                 |  (unsigned int)__builtin_bit_cast(unsigned short, lo);
  WhhP4[(k2 >> 2) * (G4 * 4) + j * 4 + (k2 & 3)] = u;
}

// reflect-padded multichannel extraction, pre-split to bf16 hi/lo: XPh/XPl[n][i]
__global__ void k_xp(const float* __restrict__ x, unsigned short* __restrict__ XPh,
                     unsigned short* __restrict__ XPl) {
  int idx = blockIdx.x * 256 + threadIdx.x;
  if (idx >= NSEQ * XPLEN) return;
  int n = idx / XPLEN, i = idx - n * XPLEN;
  int j = i - FPAD;
  if (j < 0) j = -j;
  else if (j >= LSEQ) j = 2 * LSEQ - 2 - j;
  int b = n >> 3, c = n & 7;
  float v = x[((long)b * LSEQ + j) * NCH + c];
  split_bf16(v, &XPh[idx], &XPl[idx]);
}

// ---------------- split-bf16 MFMA GEMM (fp32 A): C[M,N] = A[M,K] * Bt^T (+bias) ----------------
// kept for the small BW precompute (16 blocks)
template <int GATHER>
__launch_bounds__(256)
__global__ void k_gemm3(const float* __restrict__ A,
                        const unsigned short* __restrict__ Bth,
                        const unsigned short* __restrict__ Btl,
                        const float* __restrict__ bias, float* __restrict__ C,
                        int M, int N, int K, int lda, int ldc) {
  __shared__ __align__(16) unsigned short sAh[128 * 40];
  __shared__ __align__(16) unsigned short sAl[128 * 40];
  __shared__ __align__(16) unsigned short sBh[128 * 40];
  __shared__ __align__(16) unsigned short sBl[128 * 40];
  const int tid = threadIdx.x;
  const int row0 = blockIdx.y * 128, col0 = blockIdx.x * 128;
  const int sar = tid >> 1, sak = (tid & 1) * 16;
  const int arow = row0 + sar;
  long abase = (long)arow * lda;
  const bool arok = (arow < M);
  const int lane = tid & 63, w = tid >> 6;
  const int wm = (w >> 1) * 64, wn = (w & 1) * 64;
  const int l15 = lane & 15, quad = lane >> 4;
  f32x4 acc[4][4] = {};
  unsigned int* aH = (unsigned int*)sAh;
  unsigned int* aL = (unsigned int*)sAl;
  uint4* bH = (uint4*)sBh;
  uint4* bL = (uint4*)sBl;
  for (int k0 = 0; k0 < K; k0 += 32) {
#pragma unroll
    for (int i = 0; i < 8; i++) {
      int kk = k0 + sak + 2 * i;
      float v0 = 0.f, v1 = 0.f;
      if (arok) {
        if (kk + 1 < K) { float2 t2 = *(const float2*)(A + abase + kk); v0 = t2.x; v1 = t2.y; }
        else if (kk < K) { v0 = A[abase + kk]; }
      }
      unsigned int h0 = __float_as_uint(v0) >> 16, h1 = __float_as_uint(v1) >> 16;
      float r0 = v0 - __uint_as_float(h0 << 16), r1 = v1 - __uint_as_float(h1 << 16);
      unsigned int l0 = __float_as_uint(r0) >> 16, l1 = __float_as_uint(r1) >> 16;
      aH[sar * 20 + (sak >> 1) + i] = h0 | (h1 << 16);
      aL[sar * 20 + (sak >> 1) + i] = l0 | (l1 << 16);
    }
#pragma unroll
    for (int h = 0; h < 2; h++) {
      int idx = tid + h * 256;
      int r = idx >> 2, c = idx & 3;
      long go = (long)(col0 + r) * KPAD + k0 + c * 8;
      bH[r * 5 + c] = *(const uint4*)(Bth + go);
      bL[r * 5 + c] = *(const uint4*)(Btl + go);
    }
    __syncthreads();
    bf16x8 ah[4], al[4], bh[4], bl[4];
#pragma unroll
    for (int i = 0; i < 4; i++) {
      int off = (wm + i * 16 + l15) * 40 + quad * 8;
      ah[i] = *(const bf16x8*)(sAh + off);
      al[i] = *(const bf16x8*)(sAl + off);
      int boff = (wn + i * 16 + l15) * 40 + quad * 8;
      bh[i] = *(const bf16x8*)(sBh + boff);
      bl[i] = *(const bf16x8*)(sBl + boff);
    }
#pragma unroll
    for (int i = 0; i < 4; i++)
#pragma unroll
      for (int j = 0; j < 4; j++) {
        acc[i][j] = __builtin_amdgcn_mfma_f32_16x16x32_bf16(al[i], bh[j], acc[i][j], 0, 0, 0);
        acc[i][j] = __builtin_amdgcn_mfma_f32_16x16x32_bf16(ah[i], bl[j], acc[i][j], 0, 0, 0);
        acc[i][j] = __builtin_amdgcn_mfma_f32_16x16x32_bf16(ah[i], bh[j], acc[i][j], 0, 0, 0);
      }
    __syncthreads();
  }
#pragma unroll
  for (int i = 0; i < 4; i++)
#pragma unroll
    for (int j = 0; j < 4; j++) {
      int cc = col0 + wn + j * 16 + l15;
      if (cc >= N) continue;
      float bv = bias ? bias[cc] : 0.f;
#pragma unroll
      for (int rg = 0; rg < 4; rg++) {
        int rr = row0 + wm + i * 16 + quad * 4 + rg;
        if (rr < M) C[(long)rr * ldc + cc] = acc[i][j][rg] + bv;
      }
    }
}

// ---------------- fused STFT+xW GEMM: pre-split A (gathered XP), combined B ----------------
// C[38464, 1026]: cols <514 -> S; cols 514..1025 -> XW (+bsum). K=512, tile 128x128.
__launch_bounds__(256)
__global__ void k_gemm4(const unsigned short* __restrict__ Ah, const unsigned short* __restrict__ Al,
                        const unsigned short* __restrict__ Bh, const unsigned short* __restrict__ Bl,
                        const float* __restrict__ bsum, float* __restrict__ S,
                        float* __restrict__ XW) {
  __shared__ __align__(16) unsigned short sAh[128 * 40];
  __shared__ __align__(16) unsigned short sAl[128 * 40];
  __shared__ __align__(16) unsigned short sBh[128 * 40];
  __shared__ __align__(16) unsigned short sBl[128 * 40];
  const int tid = threadIdx.x;
  const int row0 = blockIdx.y * 128, col0 = blockIdx.x * 128;
  const int sr0 = tid >> 2, c4 = (tid & 3) * 8, cq = tid & 3;
  long ab0, ab1;
  { int rr = row0 + sr0;      int n = rr / TT, t = rr - n * TT; ab0 = (long)n * XPLEN + (long)t * HOP; }
  { int rr = row0 + sr0 + 64; int n = rr / TT, t = rr - n * TT; ab1 = (long)n * XPLEN + (long)t * HOP; }
  const int lane = tid & 63, w = tid >> 6;
  const int wm = (w >> 1) * 64, wn = (w & 1) * 64;
  const int l15 = lane & 15, quad = lane >> 4;
  f32x4 acc[4][4] = {};
  uint4* aH4 = (uint4*)sAh; uint4* aL4 = (uint4*)sAl;
  uint4* bH4 = (uint4*)sBh; uint4* bL4 = (uint4*)sBl;
  for (int k0 = 0; k0 < NFFT; k0 += 32) {
    aH4[sr0 * 5 + cq]        = *(const uint4*)(Ah + ab0 + k0 + c4);
    aL4[sr0 * 5 + cq]        = *(const uint4*)(Al + ab0 + k0 + c4);
    aH4[(sr0 + 64) * 5 + cq] = *(const uint4*)(Ah + ab1 + k0 + c4);
    aL4[(sr0 + 64) * 5 + cq] = *(const uint4*)(Al + ab1 + k0 + c4);
    {
      long go = (long)(col0 + sr0) * KPAD + k0 + c4;
      bH4[sr0 * 5 + cq] = *(const uint4*)(Bh + go);
      bL4[sr0 * 5 + cq] = *(const uint4*)(Bl + go);
      go = (long)(col0 + sr0 + 64) * KPAD + k0 + c4;
      bH4[(sr0 + 64) * 5 + cq] = *(const uint4*)(Bh + go);
      bL4[(sr0 + 64) * 5 + cq] = *(const uint4*)(Bl + go);
    }
    __syncthreads();
    bf16x8 ah[4], al[4], bh[4], bl[4];
#pragma unroll
    for (int i = 0; i < 4; i++) {
      int off = (wm + i * 16 + l15) * 40 + quad * 8;
      ah[i] = *(const bf16x8*)(sAh + off);
      al[i] = *(const bf16x8*)(sAl + off);
      int boff = (wn + i * 16 + l15) * 40 + quad * 8;
      bh[i] = *(const bf16x8*)(sBh + boff);
      bl[i] = *(const bf16x8*)(sBl + boff);
    }
#pragma unroll
    for (int i = 0; i < 4; i++)
#pragma unroll
      for (int j = 0; j < 4; j++) {
        acc[i][j] = __builtin_amdgcn_mfma_f32_16x16x32_bf16(al[i], bh[j], acc[i][j], 0, 0, 0);
        acc[i][j] = __builtin_amdgcn_mfma_f32_16x16x32_bf16(ah[i], bl[j], acc[i][j], 0, 0, 0);
        acc[i][j] = __builtin_amdgcn_mfma_f32_16x16x32_bf16(ah[i], bh[j], acc[i][j], 0, 0, 0);
      }
    __syncthreads();
  }
#pragma unroll
  for (int i = 0; i < 4; i++)
#pragma unroll
    for (int j = 0; j < 4; j++) {
      int cc = col0 + wn + j * 16 + l15;
      if (cc >= NCOMB) continue;
#pragma unroll
      for (int rg = 0; rg < 4; rg++) {
        int rr = row0 + wm + i * 16 + quad * 4 + rg;
        if (rr >= NROWS) continue;
        float v = acc[i][j][rg];
        if (cc < DD) S[(long)rr * DD + cc] = v;
        else         XW[(long)rr * G4 + (cc - 514)] = v + bsum[cc - 514];
      }
    }
}

// ---------------- iSTFT GEMM: pre-split A (pitch KPAD), B = BI split ----------------
__launch_bounds__(256)
__global__ void k_gemm5(const unsigned short* __restrict__ Ah, const unsigned short* __restrict__ Al,
                        const unsigned short* __restrict__ Bh, const unsigned short* __restrict__ Bl,
                        float* __restrict__ C, int M, int N, int ldc) {
  __shared__ __align__(16) unsigned short sAh[128 * 40];
  __shared__ __align__(16) unsigned short sAl[128 * 40];
  __shared__ __align__(16) unsigned short sBh[128 * 40];
  __shared__ __align__(16) unsigned short sBl[128 * 40];
  const int tid = threadIdx.x;
  const int row0 = blockIdx.y * 128, col0 = blockIdx.x * 128;
  const int sr0 = tid >> 2, c4 = (tid & 3) * 8, cq = tid & 3;
  const int lane = tid & 63, w = tid >> 6;
  const int wm = (w >> 1) * 64, wn = (w & 1) * 64;
  const int l15 = lane & 15, quad = lane >> 4;
  f32x4 acc[4][4] = {};
  uint4* aH4 = (uint4*)sAh; uint4* aL4 = (uint4*)sAl;
  uint4* bH4 = (uint4*)sBh; uint4* bL4 = (uint4*)sBl;
  for (int k0 = 0; k0 < KPAD; k0 += 32) {
    {
      long go = (long)(row0 + sr0) * KPAD + k0 + c4;
      aH4[sr0 * 5 + cq] = *(const uint4*)(Ah + go);
      aL4[sr0 * 5 + cq] = *(const uint4*)(Al + go);
      go = (long)(row0 + sr0 + 64) * KPAD + k0 + c4;
      aH4[(sr0 + 64) * 5 + cq] = *(const uint4*)(Ah + go);
      aL4[(sr0 + 64) * 5 + cq] = *(const uint4*)(Al + go);
    }
    {
      long go = (long)(col0 + sr0) * KPAD + k0 + c4;
      bH4[sr0 * 5 + cq] = *(const uint4*)(Bh + go);
      bL4[sr0 * 5 + cq] = *(const uint4*)(Bl + go);
      go = (long)(col0 + sr0 + 64) * KPAD + k0 + c4;
      bH4[(sr0 + 64) * 5 + cq] = *(const uint4*)(Bh + go);
      bL4[(sr0 + 64) * 5 + cq] = *(const uint4*)(Bl + go);
    }
    __syncthreads();
    bf16x8 ah[4], al[4], bh[4], bl[4];
#pragma unroll
    for (int i = 0; i < 4; i++) {
      int off = (wm + i * 16 + l15) * 40 + quad * 8;
      ah[i] = *(const bf16x8*)(sAh + off);
      al[i] = *(const bf16x8*)(sAl + off);
      int boff = (wn + i * 16 + l15) * 40 + quad * 8;
      bh[i] = *(const bf16x8*)(sBh + boff);
      bl[i] = *(const bf16x8*)(sBl + boff);
    }
#pragma unroll
    for (int i = 0; i < 4; i++)
#pragma unroll
      for (int j = 0; j < 4; j++) {
        acc[i][j] = __builtin_amdgcn_mfma_f32_16x16x32_bf16(al[i], bh[j], acc[i][j], 0, 0, 0);
        acc[i][j] = __builtin_amdgcn_mfma_f32_16x16x32_bf16(ah[i], bl[j], acc[i][j], 0, 0, 0);
        acc[i][j] = __builtin_amdgcn_mfma_f32_16x16x32_bf16(ah[i], bh[j], acc[i][j], 0, 0, 0);
      }
    __syncthreads();
  }
#pragma unroll
  for (int i = 0; i < 4; i++)
#pragma unroll
    for (int j = 0; j < 4; j++) {
      int cc = col0 + wn + j * 16 + l15;
      if (cc >= N) continue;
#pragma unroll
      for (int rg = 0; rg < 4; rg++) {
        int rr = row0 + wm + i * 16 + quad * 4 + rg;
        if (rr < M) C[(long)rr * ldc + cc] = acc[i][j][rg];
      }
    }
}

// ---------------- LSTM v8 (r10, structural plateau ~500us) ----------------
__device__ __forceinline__ float tanh_fast(float x) {
  float e = __expf(2.f * x);
  return 1.f - 2.f / (e + 1.f);
}

__launch_bounds__(512, 2)
__global__ void k_lstm(const float* __restrict__ XW, const unsigned int* __restrict__ WhhP4,
                       float* __restrict__ Hout) {
  __shared__ unsigned int hl2[64];
  __shared__ float gl[G4];
  const int j = threadIdx.x;
  const int n = blockIdx.x;
  const uint4* W4 = (const uint4*)WhhP4;
  unsigned int wp[64];
#pragma unroll
  for (int i4 = 0; i4 < 16; i4++) {
    uint4 v = W4[i4 * G4 + j];
    wp[4 * i4]     = v.x;
    wp[4 * i4 + 1] = v.y;
    wp[4 * i4 + 2] = v.z;
    wp[4 * i4 + 3] = v.w;
  }
  float cst = 0.f;
  if (j < 64) hl2[j] = 0u;
  const float* xwrow = XW + (long)n * TT * G4 + j;
  const int lane = j & 63;
  float xnext = xwrow[0];
  __syncthreads();
  for (int t = 0; t < TT; t++) {
    float xv = xnext;
    if (t + 1 < TT) xnext = xwrow[(t + 1) * G4];
    unsigned int vh = hl2[lane];
    float a0 = 0.f, a1 = 0.f, a2 = 0.f, a3 = 0.f;
#pragma unroll
    for (int q = 0; q < 16; q++) {
      unsigned int p0 = __builtin_amdgcn_readlane(vh, 4 * q);
      unsigned int p1 = __builtin_amdgcn_readlane(vh, 4 * q + 1);
      unsigned int p2 = __builtin_amdgcn_readlane(vh, 4 * q + 2);
      unsigned int p3 = __builtin_amdgcn_readlane(vh, 4 * q + 3);
      a0 = __builtin_amdgcn_fdot2(__builtin_bit_cast(h2v, p0), __builtin_bit_cast(h2v, wp[4 * q]),     a0, false);
      a1 = __builtin_amdgcn_fdot2(__builtin_bit_cast(h2v, p1), __builtin_bit_cast(h2v, wp[4 * q + 1]), a1, false);
      a2 = __builtin_amdgcn_fdot2(__builtin_bit_cast(h2v, p2), __builtin_bit_cast(h2v, wp[4 * q + 2]), a2, false);
      a3 = __builtin_amdgcn_fdot2(__builtin_bit_cast(h2v, p3), __builtin_bit_cast(h2v, wp[4 * q + 3]), a3, false);
    }
    gl[j] = ((a0 + a1) + (a2 + a3)) + xv;
    __syncthreads();
    if (j < HH) {
      float gi = gl[j], gf = gl[HH + j], gg = gl[2 * HH + j], go = gl[3 * HH + j];
      float si = 1.f / (1.f + __expf(-gi));
      float sf = 1.f / (1.f + __expf(-gf));
      float so = 1.f / (1.f + __expf(-go));
      cst = sf * cst + si * tanh_fast(gg);
      float hv = so * tanh_fast(cst);
      ((_Float16*)hl2)[j] = (_Float16)hv;
      Hout[((long)n * TT + t) * HH + j] = hv;
    }
    __syncthreads();
  }
}

// ---------------- mask GEMM (split-bf16 MFMA) + mask apply + transpose ----------------
// MS layout: [b][f][c][t] complex-interleaved (re,im)
__launch_bounds__(256)
__global__ void k_maskms(const float* __restrict__ Hout,
                         const unsigned short* __restrict__ Wsh,
                         const unsigned short* __restrict__ Wsl,
                         const float* __restrict__ bias, const float* __restrict__ S,
                         float* __restrict__ MS) {
  __shared__ __align__(16) unsigned short sAh[64 * 40];
  __shared__ __align__(16) unsigned short sAl[64 * 40];
  __shared__ __align__(16) unsigned short sBh[64 * 40];
  __shared__ __align__(16) unsigned short sBl[64 * 40];
  __shared__ float Cs[64][68];
  __shared__ float SR[64][33];
  __shared__ float SI[64][33];
  const int tid = threadIdx.x;
  const int f0 = blockIdx.x * 32;
  const int row0 = blockIdx.y * 64;
  const int lane = tid & 63, w = tid >> 6;
  const int wm = w * 16;
  const int l15 = lane & 15, quad = lane >> 4;
  const int sar = tid >> 2;
  const int sak = (tid & 3) * 8;
  const int np = ((sar < 32) ? 0 : 320 - 32) + f0 + sar;
  unsigned int* aH = (unsigned int*)sAh;
  unsigned int* aL = (unsigned int*)sAl;
  f32x4 acc[4] = {};
  for (int k0 = 0; k0 < HH; k0 += 32) {
    {
      const float* ap = Hout + (long)(row0 + sar) * HH + k0 + sak;
      float4 v0 = *(const float4*)ap;
      float4 v1 = *(const float4*)(ap + 4);
      float vv[8] = {v0.x, v0.y, v0.z, v0.w, v1.x, v1.y, v1.z, v1.w};
#pragma unroll
      for (int i = 0; i < 4; i++) {
        unsigned int h0 = __float_as_uint(vv[2 * i]) >> 16, h1 = __float_as_uint(vv[2 * i + 1]) >> 16;
        float r0 = vv[2 * i] - __uint_as_float(h0 << 16), r1 = vv[2 * i + 1] - __uint_as_float(h1 << 16);
        unsigned int l0 = __float_as_uint(r0) >> 16, l1 = __float_as_uint(r1) >> 16;
        aH[sar * 20 + (sak >> 1) + i] = h0 | (h1 << 16);
        aL[sar * 20 + (sak >> 1) + i] = l0 | (l1 << 16);
      }
    }
    {
      long go = (long)np * HH + k0 + sak;
      *(uint4*)(sBh + sar * 40 + sak) = *(const uint4*)(Wsh + go);
      *(uint4*)(sBl + sar * 40 + sak) = *(const uint4*)(Wsl + go);
    }
    __syncthreads();
    bf16x8 ah = *(const bf16x8*)(sAh + (wm + l15) * 40 + quad * 8);
    bf16x8 al = *(const bf16x8*)(sAl + (wm + l15) * 40 + quad * 8);
#pragma unroll
    for (int ct = 0; ct < 4; ct++) {
      bf16x8 bh = *(const bf16x8*)(sBh + (ct * 16 + l15) * 40 + quad * 8);
      bf16x8 bl = *(const bf16x8*)(sBl + (ct * 16 + l15) * 40 + quad * 8);
      acc[ct] = __builtin_amdgcn_mfma_f32_16x16x32_bf16(al, bh, acc[ct], 0, 0, 0);
      acc[ct] = __builtin_amdgcn_mfma_f32_16x16x32_bf16(ah, bl, acc[ct], 0, 0, 0);
      acc[ct] = __builtin_amdgcn_mfma_f32_16x16x32_bf16(ah, bh, acc[ct], 0, 0, 0);
    }
    __syncthreads();
  }
#pragma unroll
  for (int ct = 0; ct < 4; ct++) {
    int col = ct * 16 + l15;
    int f = f0 + (col & 31);
    int fcol = (col < 32) ? f : NF + f;
    float bv = (f < NF) ? bias[fcol] : 0.f;
#pragma unroll
    for (int rg = 0; rg < 4; rg++) Cs[wm + quad * 4 + rg][col] = acc[ct][rg] + bv;
  }
  __syncthreads();
  {
    int fl = tid & 31, r8 = tid >> 5;
    int f = f0 + fl;
#pragma unroll
    for (int i = 0; i < 8; i++) {
      int rl = r8 * 8 + i;
      int rr = row0 + rl;
      float rm = Cs[rl][fl], im = Cs[rl][32 + fl];
      float sr = 0.f, si = 0.f;
      if (f < NF) { sr = S[(long)rr * DD + f]; si = S[(long)rr * DD + NF + f]; }
      SR[rl][fl] = rm * sr - im * si;
      SI[rl][fl] = rm * si + im * sr;
    }
  }
  __syncthreads();
  {
    int tl = tid & 63, fq = tid >> 6;
    int rr = row0 + tl;
    int n = rr / TT, t = rr - n * TT;
    int b = n >> 3, c = n & 7;
#pragma unroll
    for (int i = 0; i < 8; i++) {
      int fl = fq * 8 + i;
      int f = f0 + fl;
      if (f < NF) {
        long addr = ((((long)b * NF + f) * 8 + c) * (long)TT + t) * 2;
        *(float2*)&MS[addr] = make_float2(SR[tl][fl], SI[tl][fl]);
      }
    }
  }
}

// ---------------- PSD: one block per (b,f); complex-interleaved MS ----------------
__launch_bounds__(256)
__global__ void k_psd(const float* __restrict__ MS, float* __restrict__ PSD) {
  __shared__ float buf[9616];
  __shared__ float part[64][8];
  const int tid = threadIdx.x;
  const long base = (long)blockIdx.x * 9616;
  for (int i = tid; i < 9616; i += 256) buf[i] = MS[base + i];
  __syncthreads();
  int p = tid & 63, q = tid >> 6;
  int c = p >> 3, e = p & 7;
  const float2* xc = (const float2*)&buf[c * 1202];
  const float2* xe = (const float2*)&buf[e * 1202];
  int t0 = q * 150, t1 = (q == 3) ? TT : t0 + 150;
  float ar = 0.f, ai = 0.f;
  for (int t = t0; t < t1; t++) {
    float2 m = xc[t];
    float2 v = xe[t];
    ar += m.x * v.x + m.y * v.y;
    ai += m.y * v.x - m.x * v.y;
  }
  part[p][q * 2] = ar; part[p][q * 2 + 1] = ai;
  __syncthreads();
  if (tid < 64) {
    float sr = part[tid][0] + part[tid][2] + part[tid][4] + part[tid][6];
    float si = part[tid][1] + part[tid][3] + part[tid][5] + part[tid][7];
    PSD[((long)blockIdx.x * 64 + tid) * 2]     = sr * (1.f / 601.f);
    PSD[((long)blockIdx.x * 64 + tid) * 2 + 1] = si * (1.f / 601.f);
  }
}

// ---------------- 8x8 complex solve + MVDR weight ----------------
__launch_bounds__(64)
__global__ void k_solve(const float* __restrict__ PS, const float* __restrict__ PN,
                        float* __restrict__ WV) {
  int idx = blockIdx.x * 64 + threadIdx.x;
  if (idx >= NB * NF) return;
  float Ar[8][8], Ai[8][8], Br[8][8], Bi[8][8];
  const float* pn = PN + (long)idx * 128;
  const float* ps = PS + (long)idx * 128;
  for (int i = 0; i < 8; i++)
    for (int j = 0; j < 8; j++) {
      Ar[i][j] = pn[(i * 8 + j) * 2]; Ai[i][j] = pn[(i * 8 + j) * 2 + 1];
      Br[i][j] = ps[(i * 8 + j) * 2]; Bi[i][j] = ps[(i * 8 + j) * 2 + 1];
    }
  float tr = 0.f;
  for (int i = 0; i < 8; i++) tr += Ar[i][i];
  float load = 1e-6f * tr / 8.f + 1e-8f;
  for (int i = 0; i < 8; i++) Ar[i][i] += load;
  for (int k = 0; k < 8; k++) {
    int piv = k; float mx = Ar[k][k] * Ar[k][k] + Ai[k][k] * Ai[k][k];
    for (int i = k + 1; i < 8; i++) {
      float m2 = Ar[i][k] * Ar[i][k] + Ai[i][k] * Ai[i][k];
      if (m2 > mx) { mx = m2; piv = i; }
    }
    if (piv != k) {
      for (int j = 0; j < 8; j++) {
        float t0;
        t0 = Ar[k][j]; Ar[k][j] = Ar[piv][j]; Ar[piv][j] = t0;
        t0 = Ai[k][j]; Ai[k][j] = Ai[piv][j]; Ai[piv][j] = t0;
        t0 = Br[k][j]; Br[k][j] = Br[piv][j]; Br[piv][j] = t0;
        t0 = Bi[k][j]; Bi[k][j] = Bi[piv][j]; Bi[piv][j] = t0;
      }
    }
    float dr = Ar[k][k], di = Ai[k][k];
    float inv = 1.f / (dr * dr + di * di);
    float irr = dr * inv, iii = -di * inv;
    for (int j = 0; j < 8; j++) {
      float xr = Ar[k][j], xi = Ai[k][j];
      Ar[k][j] = xr * irr - xi * iii; Ai[k][j] = xr * iii + xi * irr;
      xr = Br[k][j]; xi = Bi[k][j];
      Br[k][j] = xr * irr - xi * iii; Bi[k][j] = xr * iii + xi * irr;
    }
    for (int i = 0; i < 8; i++) {
      if (i == k) continue;
      float fr = Ar[i][k], fi = Ai[i][k];
      for (int j = 0; j < 8; j++) {
        float kr = Ar[k][j], ki = Ai[k][j];
        Ar[i][j] -= fr * kr - fi * ki;
        Ai[i][j] -= fr * ki + fi * kr;
        kr = Br[k][j]; ki = Bi[k][j];
        Br[i][j] -= fr * kr - fi * ki;
        Bi[i][j] -= fr * ki + fi * kr;
      }
    }
  }
  float trr = 1e-8f, tri = 0.f;
  for (int i = 0; i < 8; i++) { trr += Br[i][i]; tri += Bi[i][i]; }
  float inv = 1.f / (trr * trr + tri * tri);
  for (int c = 0; c < 8; c++) {
    float xr = Br[c][0], xi = Bi[c][0];
    WV[((long)idx * 8 + c) * 2]     = (xr * trr + xi * tri) * inv;
    WV[((long)idx * 8 + c) * 2 + 1] = (xi * trr - xr * tri) * inv;
  }
}

// ---------------- beamform -> pre-split ENH (KPAD rows) ----------------
__launch_bounds__(320)
__global__ void k_beam(const float* __restrict__ S, const float* __restrict__ WV,
                       unsigned short* __restrict__ ENHh, unsigned short* __restrict__ ENHl) {
  __shared__ float WL[NF * 16];
  int bb = blockIdx.x / TT, t = blockIdx.x - bb * TT;
  for (int i = threadIdx.x; i < NF * 16; i += 320) WL[i] = WV[(long)bb * NF * 16 + i];
  __syncthreads();
  int f = threadIdx.x;
  long base = ((long)bb * TT + t) * KPAD;
  if (f < NF) {
    float er = 0.f, ei = 0.f;
#pragma unroll
    for (int c = 0; c < 8; c++) {
      float wr = WL[(f * 8 + c) * 2], wi = WL[(f * 8 + c) * 2 + 1];
      const float* srow = S + (((long)(bb * 8 + c) * TT) + t) * DD;
      float sr = srow[f], si = srow[NF + f];
      er += wr * sr + wi * si;
      ei += wr * si - wi * sr;
    }
    split_bf16(er, &ENHh[base + f], &ENHl[base + f]);
    split_bf16(ei, &ENHh[base + NF + f], &ENHl[base + NF + f]);
  }
  int z = threadIdx.x - 288;   // threads 288..317 zero the 30 K-pad cols
  if (z >= 0 && z < 30) { ENHh[base + DD + z] = 0; ENHl[base + DD + z] = 0; }
}

// ---------------- overlap-add + normalize + crop ----------------
__global__ void k_ola(const float* __restrict__ IFR, const float* __restrict__ WSQ,
                      float* __restrict__ out) {
  int idx = blockIdx.x * 256 + threadIdx.x;
  if (idx >= NB * LSEQ) return;
  int b = idx / LSEQ, l = idx - b * LSEQ;
  int p = l + FPAD;
  int t0 = (p <= 511) ? 0 : (p - 352) / 160;
  int t1 = p / 160; if (t1 > 600) t1 = 600;
  float s = 0.f;
  for (int t = t0; t <= t1; t++) s += IFR[((long)b * TT + t) * NFFT + (p - t * HOP)];
  out[idx] = s / fmaxf(WSQ[p], 1e-11f);
}

// ---------------- driver ----------------
extern "C" void kernel_launch(void* const* d_in, const int* in_sizes, int n_in,
                              void* d_out, int out_size, void* d_ws, size_t ws_size,
                              hipStream_t stream) {
  (void)in_sizes; (void)n_in; (void)out_size; (void)ws_size;
  const float* x   = (const float*)d_in[0];
  const float* Wih = (const float*)d_in[1];
  const float* Whh = (const float*)d_in[2];
  const float* bih = (const float*)d_in[3];
  const float* bhh = (const float*)d_in[4];
  const float* W1  = (const float*)d_in[5];
  const float* b1  = (const float*)d_in[6];
  const float* W2  = (const float*)d_in[7];
  const float* b2  = (const float*)d_in[8];
  float* ws = (float*)d_ws;

  // XP region: pre-split XPh/XPl (exactly fills old XP fp32 footprint); IFR aliases later.
  unsigned short* XPh = (unsigned short*)(ws + 0);            // 6,176,768 ush = 3,088,384 fl
  unsigned short* XPl = (unsigned short*)(ws + 3088384);      // -> region ends 6,176,768 fl
  float* S     = ws + 6176768;    // 19,774,496
  float* XWM   = ws + 25951264;   // 19,774,496 (XW then MS; WhhP4 in tail)
  float* HOUT  = ws + 45725760;   // 4,924,288 (pre-GEMM scratch + post-beam ENH split live here too)
  float* PSD_S = ws + 50650048;   // 263,168
  float* PSD_N = ws + 50913216;   // 263,168
  float* WV    = ws + 51176384;   // 32,896
  float* BSUM  = ws + 51209280;   // 512
  float* WSQ   = ws + 51209792;   // 96,512 -> 51,306,304
  unsigned short* W1sh = (unsigned short*)(ws + 51306304);
  unsigned short* W1sl = (unsigned short*)(ws + 51347264);
  unsigned short* W2sh = (unsigned short*)(ws + 51388224);
  unsigned short* W2sl = (unsigned short*)(ws + 51429184); // -> 51,470,144
  unsigned short* WTth = (unsigned short*)(ws + 51470144); // 139,264 fl
  unsigned short* WTtl = (unsigned short*)(ws + 51609408); // -> 51,748,672
  unsigned short* BIth = (unsigned short*)(ws + 51748672); // 139,264 fl
  unsigned short* BItl = (unsigned short*)(ws + 51887936); // -> end 52,027,200 (~208 MB)
  float* MS    = XWM;
  float* IFR   = ws + 0;          // aliases XP region after gemm4
  unsigned int* WhhP4 = (unsigned int*)(XWM + 19693568);   // after true end of XW
  // Pre-GEMM scratch inside HOUT (dead until k_lstm):
  float* BFf = HOUT;                                        // 263,168 fl
  float* BWf = HOUT + 263168;                               // 262,144 fl
  unsigned short* BCh = (unsigned short*)(HOUT + 525312);   // 1152*544 ush = 313,344 fl
  unsigned short* BCl = (unsigned short*)(HOUT + 838656);   // -> 1,152,000 fl < 4,924,288
  // Post-beam ENH split in HOUT (Hout consumed by maskms before k_beam):
  unsigned short* ENHh = (unsigned short*)HOUT;             // 4808*544 ush = 1,307,776 fl
  unsigned short* ENHl = (unsigned short*)(HOUT + 1307776);

  k_wsq<<<(XPLEN + 255) / 256, 256, 0, stream>>>(WSQ);
  k_bff<<<(NFFT * DD + 255) / 256, 256, 0, stream>>>(BFf);
  k_wtsplit<<<(G4 * KPAD + 255) / 256, 256, 0, stream>>>(Wih, WTth, WTtl);
  k_bisplit<<<(NFFT * KPAD + 255) / 256, 256, 0, stream>>>(BIth, BItl);
  k_bsum<<<2, 256, 0, stream>>>(bih, bhh, BSUM);
  k_wmsplit<<<(2 * 640 * HH + 255) / 256, 256, 0, stream>>>(W1, W2, W1sh, W1sl, W2sh, W2sl);
  k_wpack<<<(G4 * 64 + 255) / 256, 256, 0, stream>>>(Whh, WhhP4);
  k_xp<<<(NSEQ * XPLEN + 255) / 256, 256, 0, stream>>>(x, XPh, XPl);

  // BW = BF @ Wih^T  (512x512, K=514) — small gemm3
  {
    dim3 g(4, 4);
    k_gemm3<0><<<g, 256, 0, stream>>>(BFf, WTth, WTtl, nullptr, BWf, 512, 512, DD, DD, G4);
  }
  // combined split B = [BF | BW]
  k_bcomb<<<(1152 * KPAD + 255) / 256, 256, 0, stream>>>(BWf, BCh, BCl);

  // fused STFT + xW: S[38464,514] and XW[38464,512] in one gather-GEMM
  {
    dim3 g(9, 301);
    k_gemm4<<<g, 256, 0, stream>>>(XPh, XPl, BCh, BCl, BSUM, S, XWM);
  }

  k_lstm<<<64, 512, 0, stream>>>(XWM, WhhP4, HOUT);

  dim3 gm(9, 601);
  k_maskms<<<gm, 256, 0, stream>>>(HOUT, W1sh, W1sl, b1, S, MS);
  k_psd<<<NB * NF, 256, 0, stream>>>(MS, PSD_S);
  k_maskms<<<gm, 256, 0, stream>>>(HOUT, W2sh, W2sl, b2, S, MS);
  k_psd<<<NB * NF, 256, 0, stream>>>(MS, PSD_N);

  k_solve<<<(NB * NF + 63) / 64, 64, 0, stream>>>(PSD_S, PSD_N, WV);
  k_beam<<<NB * TT, 320, 0, stream>>>(S, WV, ENHh, ENHl);

  // iSTFT: IFR[4808,512] = ENH @ BI (pre-split A)
  {
    dim3 g(4, 38);
    k_gemm5<<<g, 256, 0, stream>>>(ENHh, ENHl, BIth, BItl, IFR, NB * TT, NFFT, NFFT);
  }

  k_ola<<<(NB * LSEQ + 255) / 256, 256, 0, stream>>>(IFR, WSQ, (float*)d_out);
}